// Round 2
// baseline (2273.546 us; speedup 1.0000x reference)
//
#include <hip/hip_runtime.h>

// DTransformer forward (f32 in/out, f32 internal; V staged in LDS as bf16)
// B=2 S=512 D=256 H=8 DK=32 NK=16

namespace {
constexpr int kB = 2, kS = 512, kD = 256, kH = 8, kDK = 32, kNK = 16;
constexpr float kScale = 0.17677669529663687f;  // 1/sqrt(32)
}

typedef unsigned short u16;
typedef float f32x4 __attribute__((ext_vector_type(4)));

__device__ __forceinline__ float bf2f(u16 u) { return __uint_as_float(((unsigned)u) << 16); }
__device__ __forceinline__ u16 f2bf(float f) {
    unsigned u = __float_as_uint(f);
    return (u16)((u + 0x7fffu + ((u >> 16) & 1u)) >> 16);
}

__device__ __forceinline__ float wave_max64(float v) {
#pragma unroll
    for (int off = 32; off; off >>= 1) v = fmaxf(v, __shfl_xor(v, off));
    return v;
}
__device__ __forceinline__ float wave_sum64(float v) {
#pragma unroll
    for (int off = 32; off; off >>= 1) v += __shfl_xor(v, off);
    return v;
}

// Y[row, c] = sum_k X[row,k] * W[c,k] + bias[c]
// scatter=0: Y[row*D + c]; scatter=1: row=(b,s), c=(h,dk) -> Y[((b*H+h)*S+s)*DK+dk]
__global__ __launch_bounds__(256) void proj_kernel(const float* __restrict__ X,
                                                   const float* __restrict__ W,
                                                   const float* __restrict__ bias,
                                                   float* __restrict__ Y, int scatter) {
    const int row = blockIdx.x;
    const int c = threadIdx.x;
    __shared__ float xs[kD];
    xs[c] = X[(size_t)row * kD + c];
    __syncthreads();
    float acc = bias[c];
    const float* wr = W + (size_t)c * kD;
#pragma unroll 4
    for (int k0 = 0; k0 < kD; k0 += 4) {
        f32x4 wv = *(const f32x4*)(wr + k0);
#pragma unroll
        for (int j = 0; j < 4; ++j) acc = fmaf(xs[k0 + j], wv[j], acc);
    }
    if (scatter) {
        const int b = row >> 9, s = row & (kS - 1);
        const int h = c >> 5, dk = c & 31;
        Y[((size_t)(b * kH + h) * kS + s) * kDK + dk] = acc;
    } else {
        Y[(size_t)row * kD + c] = acc;
    }
}

// Block-1 attention: one wave per (b,h,q) row. K == Q (shared proj).
__global__ __launch_bounds__(64) void attn1_kernel(const float* __restrict__ Q1,
                                                   const float* __restrict__ V1,
                                                   const float* __restrict__ gam,
                                                   float* __restrict__ q_scores,
                                                   float* __restrict__ A1) {
    __shared__ float fs[kS];
    const int rid = blockIdx.x;          // (b*H + h)*S + q
    const int q = rid & (kS - 1);
    const int bh = rid >> 9;
    const int h = bh & (kH - 1);
    const int lane = threadIdx.x;
    const float* Kbase = Q1 + (size_t)bh * kS * kDK;
    const float* Vbase = V1 + (size_t)bh * kS * kDK;
    float qv[kDK];
#pragma unroll
    for (int d = 0; d < kDK; ++d) qv[d] = Kbase[(size_t)q * kDK + d];
    const int L = q + 1;                 // peek_cur: k <= q
    const int k0 = lane * 8;

    float sraw[8], p[8];
    float m = -3e38f;
#pragma unroll
    for (int j = 0; j < 8; ++j) {
        const int k = k0 + j;
        float s = 0.f;
        if (k < L) {
            const float* kr = Kbase + (size_t)k * kDK;
#pragma unroll
            for (int d = 0; d < kDK; ++d) s = fmaf(qv[d], kr[d], s);
            s *= kScale;
            m = fmaxf(m, s);
        }
        sraw[j] = s;
    }
    m = wave_max64(m);
    float tsum = 0.f;
#pragma unroll
    for (int j = 0; j < 8; ++j) {
        p[j] = (k0 + j < L) ? expf(sraw[j] - m) : 0.f;
        tsum += p[j];
    }
    const float tot = wave_sum64(tsum);
    const float inv_tot = 1.f / tot;
    float run = 0.f, csum[8];
#pragma unroll
    for (int j = 0; j < 8; ++j) { run += p[j] * inv_tot; csum[j] = run; }
    float inc = run;
#pragma unroll
    for (int off = 1; off < 64; off <<= 1) {
        float t = __shfl_up(inc, off);
        if (lane >= off) inc += t;
    }
    const float excl = inc - run;

    const float gh = -fabsf(gam[h]);
    float s2[8];
    float m2 = -3e38f;
#pragma unroll
    for (int j = 0; j < 8; ++j) {
        const int k = k0 + j;
        s2[j] = 0.f;
        if (k < L) {
            const float rem = 1.f - (excl + csum[j]);
            const float val = fmaxf(rem * (float)(q - k), 0.f);
            const float te = fmaxf(expf(gh * sqrtf(val)), 1e-5f);
            s2[j] = sraw[j] * te;
            m2 = fmaxf(m2, s2[j]);
        }
    }
    m2 = wave_max64(m2);
    float sum2 = 0.f;
#pragma unroll
    for (int j = 0; j < 8; ++j) {
        p[j] = (k0 + j < L) ? expf(s2[j] - m2) : 0.f;
        sum2 += p[j];
    }
    sum2 = wave_sum64(sum2);
    const float inv2 = 1.f / sum2;
    float ov[8];
#pragma unroll
    for (int j = 0; j < 8; ++j) {
        const float f = p[j] * inv2;   // maxout=False in block 1
        fs[k0 + j] = f;
        ov[j] = f;
    }
    {
        float* qrow = q_scores + (size_t)rid * kS + k0;
        *(f32x4*)(qrow) = *(f32x4*)(ov);
        *(f32x4*)(qrow + 4) = *(f32x4*)(ov + 4);
    }
    __syncthreads();

    // PV: lanes (d, half) with balanced k split
    const int d = lane & 31;
    const int Lh = (L + 1) >> 1;
    const int kb = (lane & 32) ? Lh : 0;
    const int ke = (lane & 32) ? L : Lh;
    float acc = 0.f;
    for (int k = kb; k < ke; ++k)
        acc = fmaf(fs[k], Vbase[(size_t)k * kDK + d], acc);
    acc += __shfl_xor(acc, 32);
    if (lane < 32) A1[((size_t)bh * kS + q) * kDK + d] = acc;
}

// Block-4 attention: one wave per (panel=(b*NK+nk)*H+h, q-chunk of 64).
// Raw scores are row-independent (q constant across s): computed once per block.
__global__ __launch_bounds__(64) void attn4_kernel(const float* __restrict__ Q4,
                                                   const float* __restrict__ K4,
                                                   const float* __restrict__ V4,
                                                   const float* __restrict__ gam,
                                                   float* __restrict__ k_scores,
                                                   float* __restrict__ A4) {
    __shared__ u16 Vlds[kS * kDK];
    __shared__ float raw[kS];
    __shared__ float fs[kS];
    const int panel = blockIdx.x;        // (b*NK + nk)*H + h
    const int q0 = blockIdx.y * 64;
    const int h = panel & (kH - 1);
    const int bnk = panel >> 3;
    const int nk = bnk & (kNK - 1);
    const int b = bnk >> 4;
    const int lane = threadIdx.x;

    const float* Kp = K4 + (size_t)(b * kH + h) * kS * kDK;
    const float* Vp = V4 + (size_t)(b * kH + h) * kS * kDK;

    for (int i = lane * 4; i < kS * kDK; i += 256) {
        f32x4 v = *(const f32x4*)(Vp + i);
        Vlds[i] = f2bf(v[0]); Vlds[i + 1] = f2bf(v[1]);
        Vlds[i + 2] = f2bf(v[2]); Vlds[i + 3] = f2bf(v[3]);
    }
    {
        float qv[kDK];
        const float* Qr = Q4 + (size_t)nk * kD + h * kDK;
#pragma unroll
        for (int d = 0; d < kDK; ++d) qv[d] = Qr[d];
        for (int k = lane; k < kS; k += 64) {
            const float* kr = Kp + (size_t)k * kDK;
            float s = 0.f;
#pragma unroll
            for (int d = 0; d < kDK; ++d) s = fmaf(qv[d], kr[d], s);
            raw[k] = s * kScale;
        }
    }
    __syncthreads();

    const float gh = -fabsf(gam[h]);
    const int k0 = lane * 8;

    for (int q = q0; q < q0 + 64; ++q) {
        float* krow = k_scores + ((size_t)((b * kH + h) * kS + q) * kNK + nk) * kS;
        float* arow = A4 + ((size_t)panel * kS + q) * kDK;
        const int L = q;                 // strict mask: k < q
        if (L == 0) {
            f32x4 z = {0.f, 0.f, 0.f, 0.f};
            *(f32x4*)(krow + k0) = z;
            *(f32x4*)(krow + k0 + 4) = z;
            if (lane < 32) arow[lane] = 0.f;
            continue;
        }
        float sraw[8], p[8];
        float m = -3e38f;
#pragma unroll
        for (int j = 0; j < 8; ++j) {
            const int k = k0 + j;
            const float s = (k < L) ? raw[k] : 0.f;
            sraw[j] = s;
            if (k < L) m = fmaxf(m, s);
        }
        m = wave_max64(m);
        float tsum = 0.f;
#pragma unroll
        for (int j = 0; j < 8; ++j) {
            p[j] = (k0 + j < L) ? expf(sraw[j] - m) : 0.f;
            tsum += p[j];
        }
        const float tot = wave_sum64(tsum);
        const float inv_tot = 1.f / tot;
        float run = 0.f, csum[8];
#pragma unroll
        for (int j = 0; j < 8; ++j) { run += p[j] * inv_tot; csum[j] = run; }
        float inc = run;
#pragma unroll
        for (int off = 1; off < 64; off <<= 1) {
            float t = __shfl_up(inc, off);
            if (lane >= off) inc += t;
        }
        const float excl = inc - run;

        float s2[8];
        float m2 = -3e38f;
#pragma unroll
        for (int j = 0; j < 8; ++j) {
            const int k = k0 + j;
            s2[j] = 0.f;
            if (k < L) {
                const float rem = 1.f - (excl + csum[j]);
                const float val = fmaxf(rem * (float)(L - k), 0.f);
                const float te = fmaxf(expf(gh * sqrtf(val)), 1e-5f);
                s2[j] = sraw[j] * te;
                m2 = fmaxf(m2, s2[j]);
            }
        }
        m2 = wave_max64(m2);
        float sum2 = 0.f;
#pragma unroll
        for (int j = 0; j < 8; ++j) {
            p[j] = (k0 + j < L) ? expf(s2[j] - m2) : 0.f;
            sum2 += p[j];
        }
        sum2 = wave_sum64(sum2);
        const float inv2 = 1.f / sum2;
        float mx = 0.f;
#pragma unroll
        for (int j = 0; j < 8; ++j) { p[j] *= inv2; mx = fmaxf(mx, p[j]); }
        mx = wave_max64(mx);
        const float scl = fminf(1.f / mx, 5.f);   // maxout=True
        float ov[8];
#pragma unroll
        for (int j = 0; j < 8; ++j) {
            const float f = p[j] * scl;
            fs[k0 + j] = f;
            ov[j] = f;
        }
        *(f32x4*)(krow + k0) = *(f32x4*)(ov);
        *(f32x4*)(krow + k0 + 4) = *(f32x4*)(ov + 4);
        __syncthreads();

        const int d = lane & 31;
        const int Lh = (L + 1) >> 1;
        const int kb = (lane & 32) ? Lh : 0;
        const int ke = (lane & 32) ? L : Lh;
        float acc = 0.f;
        for (int k = kb; k < ke; ++k)
            acc = fmaf(fs[k], bf2f(Vlds[k * kDK + d]), acc);
        acc += __shfl_xor(acc, 32);
        if (lane < 32) arow[d] = acc;
        __syncthreads();
    }
}

// epilogue block1: P = LN(q_emb + concat(A1) @ Wo1^T + bo1)
__global__ __launch_bounds__(256) void epi1_kernel(const float* __restrict__ A1,
                                                   const float* __restrict__ qe,
                                                   const float* __restrict__ Wo,
                                                   const float* __restrict__ bo,
                                                   const float* __restrict__ lng,
                                                   const float* __restrict__ lnb,
                                                   float* __restrict__ P) {
    const int row = blockIdx.x;          // b*S + s
    const int c = threadIdx.x;
    const int b = row >> 9, s = row & (kS - 1);
    __shared__ float xs[kD];
    const int h = c >> 5, dk = c & 31;
    xs[c] = A1[((size_t)(b * kH + h) * kS + s) * kDK + dk];
    __syncthreads();
    float acc = bo[c];
    const float* wr = Wo + (size_t)c * kD;
#pragma unroll 4
    for (int k0 = 0; k0 < kD; k0 += 4) {
        f32x4 wv = *(const f32x4*)(wr + k0);
#pragma unroll
        for (int j = 0; j < 4; ++j) acc = fmaf(xs[k0 + j], wv[j], acc);
    }
    const float x = acc + qe[(size_t)row * kD + c];
    float v1 = x, v2 = x * x;
#pragma unroll
    for (int off = 32; off; off >>= 1) { v1 += __shfl_xor(v1, off); v2 += __shfl_xor(v2, off); }
    __shared__ float rs[4], rq[4];
    const int lane = c & 63, w = c >> 6;
    if (lane == 0) { rs[w] = v1; rq[w] = v2; }
    __syncthreads();
    const float sum = rs[0] + rs[1] + rs[2] + rs[3];
    const float sq = rq[0] + rq[1] + rq[2] + rq[3];
    const float mean = sum * (1.f / kD);
    const float var = sq * (1.f / kD) - mean * mean;
    const float y = (x - mean) * rsqrtf(var + 1e-5f) * lng[c] + lnb[c];
    P[(size_t)row * kD + c] = y;
}

// epilogue block4: z = LN(know[nk] + concat(A4) @ Wo4^T + bo4), scattered to (b,s,nk,c)
__global__ __launch_bounds__(256) void epi4_kernel(const float* __restrict__ A4,
                                                   const float* __restrict__ know,
                                                   const float* __restrict__ Wo,
                                                   const float* __restrict__ bo,
                                                   const float* __restrict__ lng,
                                                   const float* __restrict__ lnb,
                                                   float* __restrict__ zout) {
    const int r = blockIdx.x;            // bnk*S + s
    const int c = threadIdx.x;
    const int bnk = r >> 9, s = r & (kS - 1);
    const int nk = bnk & (kNK - 1), b = bnk >> 4;
    __shared__ float xs[kD];
    const int h = c >> 5, dk = c & 31;
    xs[c] = A4[((size_t)(bnk * kH + h) * kS + s) * kDK + dk];
    __syncthreads();
    float acc = bo[c];
    const float* wr = Wo + (size_t)c * kD;
#pragma unroll 4
    for (int k0 = 0; k0 < kD; k0 += 4) {
        f32x4 wv = *(const f32x4*)(wr + k0);
#pragma unroll
        for (int j = 0; j < 4; ++j) acc = fmaf(xs[k0 + j], wv[j], acc);
    }
    const float x = acc + know[nk * kD + c];
    float v1 = x, v2 = x * x;
#pragma unroll
    for (int off = 32; off; off >>= 1) { v1 += __shfl_xor(v1, off); v2 += __shfl_xor(v2, off); }
    __shared__ float rs[4], rq[4];
    const int lane = c & 63, w = c >> 6;
    if (lane == 0) { rs[w] = v1; rq[w] = v2; }
    __syncthreads();
    const float sum = rs[0] + rs[1] + rs[2] + rs[3];
    const float sq = rq[0] + rq[1] + rq[2] + rq[3];
    const float mean = sum * (1.f / kD);
    const float var = sq * (1.f / kD) - mean * mean;
    const float y = (x - mean) * rsqrtf(var + 1e-5f) * lng[c] + lnb[c];
    zout[((size_t)(b * kS + s) * kNK + nk) * kD + c] = y;
}

extern "C" void kernel_launch(void* const* d_in, const int* in_sizes, int n_in,
                              void* d_out, int out_size, void* d_ws, size_t ws_size,
                              hipStream_t stream) {
    (void)in_sizes; (void)n_in; (void)out_size; (void)ws_size;

    const float* q_emb = (const float*)d_in[0];
    const float* s_emb = (const float*)d_in[1];
    // d_in[2]=s_emb_extr, d_in[3]=lens, d_in[4]=at : unused by reference
    const float* Wq1 = (const float*)d_in[5];  const float* bq1 = (const float*)d_in[6];
    const float* Wv1 = (const float*)d_in[7];  const float* bv1 = (const float*)d_in[8];
    const float* Wo1 = (const float*)d_in[9];  const float* bo1 = (const float*)d_in[10];
    const float* gam1 = (const float*)d_in[11];
    const float* ln1g = (const float*)d_in[12]; const float* ln1b = (const float*)d_in[13];
    const float* Wq4 = (const float*)d_in[14]; const float* bq4 = (const float*)d_in[15];
    const float* Wk4 = (const float*)d_in[16]; const float* bk4 = (const float*)d_in[17];
    const float* Wv4 = (const float*)d_in[18]; const float* bv4 = (const float*)d_in[19];
    const float* Wo4 = (const float*)d_in[20]; const float* bo4 = (const float*)d_in[21];
    const float* gam4 = (const float*)d_in[22];
    const float* ln4g = (const float*)d_in[23]; const float* ln4b = (const float*)d_in[24];
    const float* know = (const float*)d_in[25];

    float* ws = (float*)d_ws;
    const size_t NBHSD = (size_t)kB * kH * kS * kDK;       // 262144
    float* Q1 = ws;
    float* V1 = Q1 + NBHSD;
    float* A1 = V1 + NBHSD;
    float* P  = A1 + NBHSD;
    float* K4 = P  + (size_t)kB * kS * kD;
    float* V4 = K4 + NBHSD;
    float* Q4 = V4 + NBHSD;                                 // NK*D = 4096
    float* A4 = Q4 + (size_t)kNK * kD;                      // B*NK*H*S*DK = 4194304

    float* zout = (float*)d_out;                            // (B,S,NK*D)
    float* q_scores = zout + (size_t)kB * kS * kNK * kD;    // (B,H,S,S)
    float* k_scores = q_scores + (size_t)kB * kH * kS * kS; // (B,H,S,NK,S)

    // Block 1
    proj_kernel<<<kB * kS, 256, 0, stream>>>(q_emb, Wq1, bq1, Q1, 1);
    proj_kernel<<<kB * kS, 256, 0, stream>>>(s_emb, Wv1, bv1, V1, 1);
    attn1_kernel<<<kB * kH * kS, 64, 0, stream>>>(Q1, V1, gam1, q_scores, A1);
    epi1_kernel<<<kB * kS, 256, 0, stream>>>(A1, q_emb, Wo1, bo1, ln1g, ln1b, P);

    // Block 4 projections
    proj_kernel<<<kB * kS, 256, 0, stream>>>(q_emb, Wk4, bk4, K4, 1);
    proj_kernel<<<kB * kS, 256, 0, stream>>>(P, Wv4, bv4, V4, 1);
    proj_kernel<<<kNK, 256, 0, stream>>>(know, Wq4, bq4, Q4, 0);

    // Block 4 attention + epilogue
    dim3 g5(kB * kNK * kH, kS / 64);
    attn4_kernel<<<g5, 64, 0, stream>>>(Q4, K4, V4, gam4, k_scores, A4);
    epi4_kernel<<<kB * kNK * kS, 256, 0, stream>>>(A4, know, Wo4, bo4, ln4g, ln4b, zout);
}

// Round 3
// 976.939 us; speedup vs baseline: 2.3272x; 2.3272x over previous
//
#include <hip/hip_runtime.h>

// DTransformer forward (f32 in/out, f32 internal; V staged in LDS as bf16)
// B=2 S=512 D=256 H=8 DK=32 NK=16

namespace {
constexpr int kB = 2, kS = 512, kD = 256, kH = 8, kDK = 32, kNK = 16;
constexpr float kScale = 0.17677669529663687f;  // 1/sqrt(32)
}

typedef unsigned short u16;
typedef u16 u16x4 __attribute__((ext_vector_type(4)));
typedef float f32x4 __attribute__((ext_vector_type(4)));

__device__ __forceinline__ float bf2f(u16 u) { return __uint_as_float(((unsigned)u) << 16); }
__device__ __forceinline__ u16 f2bf(float f) {
    unsigned u = __float_as_uint(f);
    return (u16)((u + 0x7fffu + ((u >> 16) & 1u)) >> 16);
}

__device__ __forceinline__ float wave_max64(float v) {
#pragma unroll
    for (int off = 32; off; off >>= 1) v = fmaxf(v, __shfl_xor(v, off));
    return v;
}
__device__ __forceinline__ float wave_sum64(float v) {
#pragma unroll
    for (int off = 32; off; off >>= 1) v += __shfl_xor(v, off);
    return v;
}

// Y[row, c] = sum_k X[row,k] * W[c,k] + bias[c]
// scatter=0: Y[row*D + c]; scatter=1: row=(b,s), c=(h,dk) -> Y[((b*H+h)*S+s)*DK+dk]
__global__ __launch_bounds__(256) void proj_kernel(const float* __restrict__ X,
                                                   const float* __restrict__ W,
                                                   const float* __restrict__ bias,
                                                   float* __restrict__ Y, int scatter) {
    const int row = blockIdx.x;
    const int c = threadIdx.x;
    __shared__ float xs[kD];
    xs[c] = X[(size_t)row * kD + c];
    __syncthreads();
    float acc = bias[c];
    const float* wr = W + (size_t)c * kD;
#pragma unroll 4
    for (int k0 = 0; k0 < kD; k0 += 4) {
        f32x4 wv = *(const f32x4*)(wr + k0);
#pragma unroll
        for (int j = 0; j < 4; ++j) acc = fmaf(xs[k0 + j], wv[j], acc);
    }
    if (scatter) {
        const int b = row >> 9, s = row & (kS - 1);
        const int h = c >> 5, dk = c & 31;
        Y[((size_t)(b * kH + h) * kS + s) * kDK + dk] = acc;
    } else {
        Y[(size_t)row * kD + c] = acc;
    }
}

// Block-1 attention: one wave per (b,h,q) row. K == Q (shared proj).
__global__ __launch_bounds__(64) void attn1_kernel(const float* __restrict__ Q1,
                                                   const float* __restrict__ V1,
                                                   const float* __restrict__ gam,
                                                   float* __restrict__ q_scores,
                                                   float* __restrict__ A1) {
    __shared__ float fs[kS];
    const int rid = blockIdx.x;          // (b*H + h)*S + q
    const int q = rid & (kS - 1);
    const int bh = rid >> 9;
    const int h = bh & (kH - 1);
    const int lane = threadIdx.x;
    const float* Kbase = Q1 + (size_t)bh * kS * kDK;
    const float* Vbase = V1 + (size_t)bh * kS * kDK;
    float qv[kDK];
#pragma unroll
    for (int d = 0; d < kDK; ++d) qv[d] = Kbase[(size_t)q * kDK + d];
    const int L = q + 1;                 // peek_cur: k <= q
    const int k0 = lane * 8;

    float sraw[8], p[8];
    float m = -3e38f;
#pragma unroll
    for (int j = 0; j < 8; ++j) {
        const int k = k0 + j;
        float s = 0.f;
        if (k < L) {
            const float* kr = Kbase + (size_t)k * kDK;
#pragma unroll
            for (int d = 0; d < kDK; ++d) s = fmaf(qv[d], kr[d], s);
            s *= kScale;
            m = fmaxf(m, s);
        }
        sraw[j] = s;
    }
    m = wave_max64(m);
    float tsum = 0.f;
#pragma unroll
    for (int j = 0; j < 8; ++j) {
        p[j] = (k0 + j < L) ? __expf(sraw[j] - m) : 0.f;
        tsum += p[j];
    }
    const float tot = wave_sum64(tsum);
    const float inv_tot = 1.f / tot;
    float run = 0.f, csum[8];
#pragma unroll
    for (int j = 0; j < 8; ++j) { run += p[j] * inv_tot; csum[j] = run; }
    float inc = run;
#pragma unroll
    for (int off = 1; off < 64; off <<= 1) {
        float t = __shfl_up(inc, off);
        if (lane >= off) inc += t;
    }
    const float excl = inc - run;

    const float gh = -fabsf(gam[h]);
    float s2[8];
    float m2 = -3e38f;
#pragma unroll
    for (int j = 0; j < 8; ++j) {
        const int k = k0 + j;
        s2[j] = 0.f;
        if (k < L) {
            const float rem = 1.f - (excl + csum[j]);
            const float val = fmaxf(rem * (float)(q - k), 0.f);
            const float te = fmaxf(__expf(gh * sqrtf(val)), 1e-5f);
            s2[j] = sraw[j] * te;
            m2 = fmaxf(m2, s2[j]);
        }
    }
    m2 = wave_max64(m2);
    float sum2 = 0.f;
#pragma unroll
    for (int j = 0; j < 8; ++j) {
        p[j] = (k0 + j < L) ? __expf(s2[j] - m2) : 0.f;
        sum2 += p[j];
    }
    sum2 = wave_sum64(sum2);
    const float inv2 = 1.f / sum2;
    float ov[8];
#pragma unroll
    for (int j = 0; j < 8; ++j) {
        const float f = p[j] * inv2;   // maxout=False in block 1
        fs[k0 + j] = f;
        ov[j] = f;
    }
    {
        float* qrow = q_scores + (size_t)rid * kS + k0;
        *(f32x4*)(qrow) = *(f32x4*)(ov);
        *(f32x4*)(qrow + 4) = *(f32x4*)(ov + 4);
    }
    __syncthreads();

    // PV: lanes (d, half) with balanced k split
    const int d = lane & 31;
    const int Lh = (L + 1) >> 1;
    const int kb = (lane & 32) ? Lh : 0;
    const int ke = (lane & 32) ? L : Lh;
    float acc = 0.f;
    for (int k = kb; k < ke; ++k)
        acc = fmaf(fs[k], Vbase[(size_t)k * kDK + d], acc);
    acc += __shfl_xor(acc, 32);
    if (lane < 32) A1[((size_t)bh * kS + q) * kDK + d] = acc;
}

// Block-4 prep: per panel (b,nk,h): raw scores (length S), stabilized exp, prefix sums.
__global__ __launch_bounds__(64) void attn4_prep(const float* __restrict__ Q4,
                                                 const float* __restrict__ K4,
                                                 float* __restrict__ rawP,
                                                 float* __restrict__ CpreP) {
    const int panel = blockIdx.x;        // (b*NK + nk)*H + h
    const int h = panel & (kH - 1);
    const int bnk = panel >> 3;
    const int nk = bnk & (kNK - 1);
    const int b = bnk >> 4;
    const int lane = threadIdx.x;
    const float* Kp = K4 + (size_t)(b * kH + h) * kS * kDK;
    float qv[kDK];
    const float* Qr = Q4 + (size_t)nk * kD + h * kDK;
#pragma unroll
    for (int d = 0; d < kDK; ++d) qv[d] = Qr[d];

    const int k0 = lane * 8;
    float raw[8];
    float m = -3e38f;
#pragma unroll
    for (int j = 0; j < 8; ++j) {
        const float* kr = Kp + (size_t)(k0 + j) * kDK;
        float s = 0.f;
#pragma unroll
        for (int d = 0; d < kDK; ++d) s = fmaf(qv[d], kr[d], s);
        raw[j] = s * kScale;
        m = fmaxf(m, raw[j]);
    }
    m = wave_max64(m);
    float E[8];
    float s = 0.f;
#pragma unroll
    for (int j = 0; j < 8; ++j) { E[j] = __expf(raw[j] - m); s += E[j]; }
    float inc = s;
#pragma unroll
    for (int off = 1; off < 64; off <<= 1) {
        float t = __shfl_up(inc, off);
        if (lane >= off) inc += t;
    }
    float run = inc - s;   // exclusive prefix of lane sums
    float cp[8];
#pragma unroll
    for (int j = 0; j < 8; ++j) { run += E[j]; cp[j] = run; }

    float* rrow = rawP + (size_t)panel * kS + k0;
    float* crow = CpreP + (size_t)panel * kS + k0;
    *(f32x4*)(rrow) = *(f32x4*)(raw);
    *(f32x4*)(rrow + 4) = *(f32x4*)(raw + 4);
    *(f32x4*)(crow) = *(f32x4*)(cp);
    *(f32x4*)(crow + 4) = *(f32x4*)(cp + 4);
}

// Block-4 main: 4 waves/block, one q-row per wave per iteration, no barriers in loop.
__global__ __launch_bounds__(256) void attn4_main(const float* __restrict__ rawP,
                                                  const float* __restrict__ CpreP,
                                                  const float* __restrict__ V4,
                                                  const float* __restrict__ gam,
                                                  float* __restrict__ k_scores,
                                                  float* __restrict__ A4) {
    __shared__ u16 Vlds[kS * kDK];       // 32 KB
    __shared__ float raws[kS];           // 2 KB
    __shared__ float cps[kS];            // 2 KB
    __shared__ float fsb[4][kS];         // 8 KB
    const int panel = blockIdx.x;        // (b*NK + nk)*H + h
    const int q0 = blockIdx.y * 64;
    const int h = panel & (kH - 1);
    const int bnk = panel >> 3;
    const int nk = bnk & (kNK - 1);
    const int b = bnk >> 4;
    const int tid = threadIdx.x;
    const int lane = tid & 63;
    const int w = tid >> 6;

    const float* Vp = V4 + (size_t)(b * kH + h) * kS * kDK;
    for (int i = tid * 4; i < kS * kDK; i += 1024) {
        f32x4 v = *(const f32x4*)(Vp + i);
        u16x4 pk = {f2bf(v[0]), f2bf(v[1]), f2bf(v[2]), f2bf(v[3])};
        *(u16x4*)(Vlds + i) = pk;
    }
    for (int i = tid; i < kS; i += 256) {
        raws[i] = rawP[(size_t)panel * kS + i];
        cps[i] = CpreP[(size_t)panel * kS + i];
    }
    __syncthreads();

    const float gh = -fabsf(gam[h]);
    const int k0 = lane * 8;
    // row-invariant per-lane data
    float rw[8], cp[8];
    *(f32x4*)(rw) = *(const f32x4*)(raws + k0);
    *(f32x4*)(rw + 4) = *(const f32x4*)(raws + k0 + 4);
    *(f32x4*)(cp) = *(const f32x4*)(cps + k0);
    *(f32x4*)(cp + 4) = *(const f32x4*)(cps + k0 + 4);

    float* fw = fsb[w];
    const int d = lane & 31;
    const int half = lane >> 5;

    for (int i = 0; i < 16; ++i) {
        const int q = q0 + w * 16 + i;
        float* krow = k_scores + ((size_t)((b * kH + h) * kS + q) * kNK + nk) * kS;
        float* arow = A4 + ((size_t)panel * kS + q) * kDK;
        const int L = q;                 // strict mask: k < q
        if (L == 0) {
            f32x4 z = {0.f, 0.f, 0.f, 0.f};
            *(f32x4*)(krow + k0) = z;
            *(f32x4*)(krow + k0 + 4) = z;
            if (lane < 32) arow[lane] = 0.f;
            continue;
        }
        const float invCL = 1.f / cps[L - 1];
        float p[8];
        float m2 = -3e38f;
#pragma unroll
        for (int j = 0; j < 8; ++j) {
            const int k = k0 + j;
            float s2 = 0.f;
            if (k < L) {
                const float rem = 1.f - cp[j] * invCL;
                const float val = fmaxf(rem * (float)(L - k), 0.f);
                const float te = fmaxf(__expf(gh * sqrtf(val)), 1e-5f);
                s2 = rw[j] * te;
                m2 = fmaxf(m2, s2);
            }
            p[j] = s2;
        }
        m2 = wave_max64(m2);
        float sum2 = 0.f;
#pragma unroll
        for (int j = 0; j < 8; ++j) {
            p[j] = (k0 + j < L) ? __expf(p[j] - m2) : 0.f;
            sum2 += p[j];
        }
        sum2 = wave_sum64(sum2);
        const float inv2 = 1.f / sum2;
        float mx = 0.f;
#pragma unroll
        for (int j = 0; j < 8; ++j) { p[j] *= inv2; mx = fmaxf(mx, p[j]); }
        mx = wave_max64(mx);
        const float scl = fminf(1.f / mx, 5.f);   // maxout=True
#pragma unroll
        for (int j = 0; j < 8; ++j) p[j] *= scl;
        *(f32x4*)(krow + k0) = *(f32x4*)(p);
        *(f32x4*)(krow + k0 + 4) = *(f32x4*)(p + 4);
        *(f32x4*)(fw + k0) = *(f32x4*)(p);
        *(f32x4*)(fw + k0 + 4) = *(f32x4*)(p + 4);

        // PV: halves split k-range at 4-aligned midpoint; f32x4 fs broadcasts
        int Lh = ((L >> 1) + 3) & ~3;
        if (Lh > L) Lh = L;
        const int kb = half ? Lh : 0;
        const int ke = half ? L : Lh;
        float acc = 0.f;
        int k = kb;
        for (; k + 4 <= ke; k += 4) {
            f32x4 fv = *(const f32x4*)(fw + k);
            const int base = k * kDK + d;
            acc = fmaf(fv[0], bf2f(Vlds[base]), acc);
            acc = fmaf(fv[1], bf2f(Vlds[base + 32]), acc);
            acc = fmaf(fv[2], bf2f(Vlds[base + 64]), acc);
            acc = fmaf(fv[3], bf2f(Vlds[base + 96]), acc);
        }
        for (; k < ke; ++k) acc = fmaf(fw[k], bf2f(Vlds[k * kDK + d]), acc);
        acc += __shfl_xor(acc, 32);
        if (lane < 32) arow[d] = acc;
    }
}

// epilogue block1: P = LN(q_emb + concat(A1) @ Wo1^T + bo1)
__global__ __launch_bounds__(256) void epi1_kernel(const float* __restrict__ A1,
                                                   const float* __restrict__ qe,
                                                   const float* __restrict__ Wo,
                                                   const float* __restrict__ bo,
                                                   const float* __restrict__ lng,
                                                   const float* __restrict__ lnb,
                                                   float* __restrict__ P) {
    const int row = blockIdx.x;          // b*S + s
    const int c = threadIdx.x;
    const int b = row >> 9, s = row & (kS - 1);
    __shared__ float xs[kD];
    const int h = c >> 5, dk = c & 31;
    xs[c] = A1[((size_t)(b * kH + h) * kS + s) * kDK + dk];
    __syncthreads();
    float acc = bo[c];
    const float* wr = Wo + (size_t)c * kD;
#pragma unroll 4
    for (int k0 = 0; k0 < kD; k0 += 4) {
        f32x4 wv = *(const f32x4*)(wr + k0);
#pragma unroll
        for (int j = 0; j < 4; ++j) acc = fmaf(xs[k0 + j], wv[j], acc);
    }
    const float x = acc + qe[(size_t)row * kD + c];
    float v1 = x, v2 = x * x;
#pragma unroll
    for (int off = 32; off; off >>= 1) { v1 += __shfl_xor(v1, off); v2 += __shfl_xor(v2, off); }
    __shared__ float rs[4], rq[4];
    const int lane = c & 63, w = c >> 6;
    if (lane == 0) { rs[w] = v1; rq[w] = v2; }
    __syncthreads();
    const float sum = rs[0] + rs[1] + rs[2] + rs[3];
    const float sq = rq[0] + rq[1] + rq[2] + rq[3];
    const float mean = sum * (1.f / kD);
    const float var = sq * (1.f / kD) - mean * mean;
    const float y = (x - mean) * rsqrtf(var + 1e-5f) * lng[c] + lnb[c];
    P[(size_t)row * kD + c] = y;
}

// epilogue block4: z = LN(know[nk] + concat(A4) @ Wo4^T + bo4), scattered to (b,s,nk,c)
__global__ __launch_bounds__(256) void epi4_kernel(const float* __restrict__ A4,
                                                   const float* __restrict__ know,
                                                   const float* __restrict__ Wo,
                                                   const float* __restrict__ bo,
                                                   const float* __restrict__ lng,
                                                   const float* __restrict__ lnb,
                                                   float* __restrict__ zout) {
    const int r = blockIdx.x;            // bnk*S + s
    const int c = threadIdx.x;
    const int bnk = r >> 9, s = r & (kS - 1);
    const int nk = bnk & (kNK - 1), b = bnk >> 4;
    __shared__ float xs[kD];
    const int h = c >> 5, dk = c & 31;
    xs[c] = A4[((size_t)(bnk * kH + h) * kS + s) * kDK + dk];
    __syncthreads();
    float acc = bo[c];
    const float* wr = Wo + (size_t)c * kD;
#pragma unroll 4
    for (int k0 = 0; k0 < kD; k0 += 4) {
        f32x4 wv = *(const f32x4*)(wr + k0);
#pragma unroll
        for (int j = 0; j < 4; ++j) acc = fmaf(xs[k0 + j], wv[j], acc);
    }
    const float x = acc + know[nk * kD + c];
    float v1 = x, v2 = x * x;
#pragma unroll
    for (int off = 32; off; off >>= 1) { v1 += __shfl_xor(v1, off); v2 += __shfl_xor(v2, off); }
    __shared__ float rs[4], rq[4];
    const int lane = c & 63, w = c >> 6;
    if (lane == 0) { rs[w] = v1; rq[w] = v2; }
    __syncthreads();
    const float sum = rs[0] + rs[1] + rs[2] + rs[3];
    const float sq = rq[0] + rq[1] + rq[2] + rq[3];
    const float mean = sum * (1.f / kD);
    const float var = sq * (1.f / kD) - mean * mean;
    const float y = (x - mean) * rsqrtf(var + 1e-5f) * lng[c] + lnb[c];
    zout[((size_t)(b * kS + s) * kNK + nk) * kD + c] = y;
}

extern "C" void kernel_launch(void* const* d_in, const int* in_sizes, int n_in,
                              void* d_out, int out_size, void* d_ws, size_t ws_size,
                              hipStream_t stream) {
    (void)in_sizes; (void)n_in; (void)out_size; (void)ws_size;

    const float* q_emb = (const float*)d_in[0];
    const float* s_emb = (const float*)d_in[1];
    // d_in[2]=s_emb_extr, d_in[3]=lens, d_in[4]=at : unused by reference
    const float* Wq1 = (const float*)d_in[5];  const float* bq1 = (const float*)d_in[6];
    const float* Wv1 = (const float*)d_in[7];  const float* bv1 = (const float*)d_in[8];
    const float* Wo1 = (const float*)d_in[9];  const float* bo1 = (const float*)d_in[10];
    const float* gam1 = (const float*)d_in[11];
    const float* ln1g = (const float*)d_in[12]; const float* ln1b = (const float*)d_in[13];
    const float* Wq4 = (const float*)d_in[14]; const float* bq4 = (const float*)d_in[15];
    const float* Wk4 = (const float*)d_in[16]; const float* bk4 = (const float*)d_in[17];
    const float* Wv4 = (const float*)d_in[18]; const float* bv4 = (const float*)d_in[19];
    const float* Wo4 = (const float*)d_in[20]; const float* bo4 = (const float*)d_in[21];
    const float* gam4 = (const float*)d_in[22];
    const float* ln4g = (const float*)d_in[23]; const float* ln4b = (const float*)d_in[24];
    const float* know = (const float*)d_in[25];

    float* ws = (float*)d_ws;
    const size_t NBHSD = (size_t)kB * kH * kS * kDK;       // 262144
    float* Q1 = ws;
    float* V1 = Q1 + NBHSD;                                 // freed after attn1 -> rawP/CpreP
    float* A1 = V1 + NBHSD;
    float* P  = A1 + NBHSD;
    float* K4 = P  + (size_t)kB * kS * kD;
    float* V4 = K4 + NBHSD;
    float* Q4 = V4 + NBHSD;                                 // NK*D = 4096
    float* A4 = Q4 + (size_t)kNK * kD;                      // B*NK*H*S*DK = 4194304

    float* rawP = V1;                                       // 256*512 floats
    float* CpreP = V1 + (size_t)kB * kNK * kH * kS;         // 256*512 floats

    float* zout = (float*)d_out;                            // (B,S,NK*D)
    float* q_scores = zout + (size_t)kB * kS * kNK * kD;    // (B,H,S,S)
    float* k_scores = q_scores + (size_t)kB * kH * kS * kS; // (B,H,S,NK,S)

    // Block 1
    proj_kernel<<<kB * kS, 256, 0, stream>>>(q_emb, Wq1, bq1, Q1, 1);
    proj_kernel<<<kB * kS, 256, 0, stream>>>(s_emb, Wv1, bv1, V1, 1);
    attn1_kernel<<<kB * kH * kS, 64, 0, stream>>>(Q1, V1, gam1, q_scores, A1);
    epi1_kernel<<<kB * kS, 256, 0, stream>>>(A1, q_emb, Wo1, bo1, ln1g, ln1b, P);

    // Block 4 projections (V1 dead from here; reused as rawP/CpreP)
    proj_kernel<<<kB * kS, 256, 0, stream>>>(q_emb, Wk4, bk4, K4, 1);
    proj_kernel<<<kB * kS, 256, 0, stream>>>(P, Wv4, bv4, V4, 1);
    proj_kernel<<<kNK, 256, 0, stream>>>(know, Wq4, bq4, Q4, 0);

    // Block 4 attention + epilogue
    attn4_prep<<<kB * kNK * kH, 64, 0, stream>>>(Q4, K4, rawP, CpreP);
    dim3 g5(kB * kNK * kH, kS / 64);
    attn4_main<<<g5, 256, 0, stream>>>(rawP, CpreP, V4, gam4, k_scores, A4);
    epi4_kernel<<<kB * kNK * kS, 256, 0, stream>>>(A4, know, Wo4, bo4, ln4g, ln4b, zout);
}

// Round 4
// 513.667 us; speedup vs baseline: 4.4261x; 1.9019x over previous
//
#include <hip/hip_runtime.h>

// DTransformer forward (f32 in/out, f32 internal; V staged in LDS as bf16)
// B=2 S=512 D=256 H=8 DK=32 NK=16

namespace {
constexpr int kB = 2, kS = 512, kD = 256, kH = 8, kDK = 32, kNK = 16;
constexpr float kScale = 0.17677669529663687f;  // 1/sqrt(32)
}

typedef unsigned short u16;
typedef u16 u16x4 __attribute__((ext_vector_type(4)));
typedef float f32x4 __attribute__((ext_vector_type(4)));

__device__ __forceinline__ float bf2f(u16 u) { return __uint_as_float(((unsigned)u) << 16); }
__device__ __forceinline__ u16 f2bf(float f) {
    unsigned u = __float_as_uint(f);
    return (u16)((u + 0x7fffu + ((u >> 16) & 1u)) >> 16);
}

__device__ __forceinline__ float wave_max64(float v) {
#pragma unroll
    for (int off = 32; off; off >>= 1) v = fmaxf(v, __shfl_xor(v, off));
    return v;
}
__device__ __forceinline__ float wave_sum64(float v) {
#pragma unroll
    for (int off = 32; off; off >>= 1) v += __shfl_xor(v, off);
    return v;
}

// Transpose 6 weight matrices [c][k] -> [k][c] (256x256 each)
__global__ __launch_bounds__(256) void wt_kernel(const float* __restrict__ W0,
                                                 const float* __restrict__ W1,
                                                 const float* __restrict__ W2,
                                                 const float* __restrict__ W3,
                                                 const float* __restrict__ W4,
                                                 const float* __restrict__ W5,
                                                 float* __restrict__ WT) {
    const float* srcs[6] = {W0, W1, W2, W3, W4, W5};
    const float* W = srcs[blockIdx.y];
    float* T = WT + (size_t)blockIdx.y * kD * kD;
    const int k = blockIdx.x, c = threadIdx.x;
    T[(size_t)k * kD + c] = W[(size_t)c * kD + k];
}

// Unified tiled GEMM: Y[row,c] = sum_k X[row,k]*W[c,k] + bias[c], W given transposed.
// MODE 0: X plain [row][256], Y scattered to [(row>>9)*8+h][s][dk]
// MODE 1: X gathered from A-layout, +extra[row][c] residual, LN, Y plain [row][256]
// MODE 2: X gathered from A-layout, +extra[nk][c], LN, Y scattered to [(b,s,nk)][c]
template <int RPW, int MODE>
__global__ __launch_bounds__(256) void gemm256(const float* __restrict__ X,
                                               const float* __restrict__ WT,
                                               const float* __restrict__ bias,
                                               const float* __restrict__ extra,
                                               const float* __restrict__ lng,
                                               const float* __restrict__ lnb,
                                               float* __restrict__ Y) {
    constexpr int TM = RPW * 4;
    __shared__ float xs[TM][kD];
    const int t = threadIdx.x;
    const int r0 = blockIdx.x * TM;

    if (MODE == 0) {
#pragma unroll
        for (int it = 0; it < RPW; ++it) {
            const int idx = it * 1024 + t * 4;
            const int r = idx >> 8, c = idx & 255;
            *(f32x4*)&xs[r][c] = *(const f32x4*)(X + (size_t)(r0 + r) * kD + c);
        }
    } else {
        // gather from [(grp*8+h)*512 + s]*32 + dk, row = grp*512+s
#pragma unroll
        for (int it = 0; it < RPW; ++it) {
            const int chunk = it * 32 + (t >> 3);   // 0..TM*8-1
            const int r = chunk >> 3, h = chunk & 7;
            const int row = r0 + r;
            const float* src = X + (((size_t)(row >> 9) * kH + h) * kS + (row & (kS - 1))) * kDK + (t & 7) * 4;
            *(f32x4*)&xs[r][h * kDK + (t & 7) * 4] = *(const f32x4*)src;
        }
    }
    __syncthreads();

    const int wv = t >> 6;
    const int c4 = (t & 63) * 4;
    float acc[RPW][4];
    {
        f32x4 bv = *(const f32x4*)(bias + c4);
#pragma unroll
        for (int r = 0; r < RPW; ++r)
#pragma unroll
            for (int j = 0; j < 4; ++j) acc[r][j] = bv[j];
    }
    for (int k0 = 0; k0 < kD; k0 += 4) {
        f32x4 w0 = *(const f32x4*)(WT + (size_t)(k0 + 0) * kD + c4);
        f32x4 w1 = *(const f32x4*)(WT + (size_t)(k0 + 1) * kD + c4);
        f32x4 w2 = *(const f32x4*)(WT + (size_t)(k0 + 2) * kD + c4);
        f32x4 w3 = *(const f32x4*)(WT + (size_t)(k0 + 3) * kD + c4);
#pragma unroll
        for (int r = 0; r < RPW; ++r) {
            f32x4 xv = *(const f32x4*)&xs[wv * RPW + r][k0];
#pragma unroll
            for (int cc = 0; cc < 4; ++cc) {
                acc[r][cc] = fmaf(xv[0], w0[cc], acc[r][cc]);
                acc[r][cc] = fmaf(xv[1], w1[cc], acc[r][cc]);
                acc[r][cc] = fmaf(xv[2], w2[cc], acc[r][cc]);
                acc[r][cc] = fmaf(xv[3], w3[cc], acc[r][cc]);
            }
        }
    }

#pragma unroll
    for (int r = 0; r < RPW; ++r) {
        const int row = r0 + wv * RPW + r;
        if (MODE == 0) {
            const int h = c4 >> 5, dk = c4 & 31;
            *(f32x4*)(Y + (((size_t)(row >> 9) * kH + h) * kS + (row & (kS - 1))) * kDK + dk) =
                *(f32x4*)acc[r];
        } else {
            f32x4 x;
            if (MODE == 1) {
                f32x4 e = *(const f32x4*)(extra + (size_t)row * kD + c4);
#pragma unroll
                for (int j = 0; j < 4; ++j) x[j] = acc[r][j] + e[j];
            } else {
                const int nk = (row >> 9) & (kNK - 1);
                f32x4 e = *(const f32x4*)(extra + (size_t)nk * kD + c4);
#pragma unroll
                for (int j = 0; j < 4; ++j) x[j] = acc[r][j] + e[j];
            }
            float s1 = x[0] + x[1] + x[2] + x[3];
            float s2 = x[0] * x[0] + x[1] * x[1] + x[2] * x[2] + x[3] * x[3];
#pragma unroll
            for (int off = 32; off; off >>= 1) {
                s1 += __shfl_xor(s1, off);
                s2 += __shfl_xor(s2, off);
            }
            const float mean = s1 * (1.f / kD);
            const float var = s2 * (1.f / kD) - mean * mean;
            const float rstd = rsqrtf(var + 1e-5f);
            f32x4 g = *(const f32x4*)(lng + c4);
            f32x4 bb = *(const f32x4*)(lnb + c4);
            f32x4 y;
#pragma unroll
            for (int j = 0; j < 4; ++j) y[j] = (x[j] - mean) * rstd * g[j] + bb[j];
            if (MODE == 1) {
                *(f32x4*)(Y + (size_t)row * kD + c4) = y;
            } else {
                const int bnk = row >> 9, s = row & (kS - 1);
                const int nk = bnk & (kNK - 1), b = bnk >> 4;
                *(f32x4*)(Y + (((size_t)(b * kS + s) * kNK + nk) * kD) + c4) = y;
            }
        }
    }
}

// one-row-per-block projection (kept only for tiny Q4: 16 rows)
__global__ __launch_bounds__(256) void proj_kernel(const float* __restrict__ X,
                                                   const float* __restrict__ W,
                                                   const float* __restrict__ bias,
                                                   float* __restrict__ Y, int scatter) {
    const int row = blockIdx.x;
    const int c = threadIdx.x;
    __shared__ float xs[kD];
    xs[c] = X[(size_t)row * kD + c];
    __syncthreads();
    float acc = bias[c];
    const float* wr = W + (size_t)c * kD;
#pragma unroll 4
    for (int k0 = 0; k0 < kD; k0 += 4) {
        f32x4 wv = *(const f32x4*)(wr + k0);
#pragma unroll
        for (int j = 0; j < 4; ++j) acc = fmaf(xs[k0 + j], wv[j], acc);
    }
    if (scatter) {
        const int b = row >> 9, s = row & (kS - 1);
        const int h = c >> 5, dk = c & 31;
        Y[((size_t)(b * kH + h) * kS + s) * kDK + dk] = acc;
    } else {
        Y[(size_t)row * kD + c] = acc;
    }
}

// Block-1 attention: one wave per (b,h,q) row. K == Q (shared proj).
__global__ __launch_bounds__(64) void attn1_kernel(const float* __restrict__ Q1,
                                                   const float* __restrict__ V1,
                                                   const float* __restrict__ gam,
                                                   float* __restrict__ q_scores,
                                                   float* __restrict__ A1) {
    __shared__ float fs[kS];
    const int rid = blockIdx.x;          // (b*H + h)*S + q
    const int q = rid & (kS - 1);
    const int bh = rid >> 9;
    const int h = bh & (kH - 1);
    const int lane = threadIdx.x;
    const float* Kbase = Q1 + (size_t)bh * kS * kDK;
    const float* Vbase = V1 + (size_t)bh * kS * kDK;
    float qv[kDK];
#pragma unroll
    for (int d = 0; d < kDK; ++d) qv[d] = Kbase[(size_t)q * kDK + d];
    const int L = q + 1;                 // peek_cur: k <= q
    const int k0 = lane * 8;

    float sraw[8], p[8];
    float m = -3e38f;
#pragma unroll
    for (int j = 0; j < 8; ++j) {
        const int k = k0 + j;
        float s = 0.f;
        if (k < L) {
            const float* kr = Kbase + (size_t)k * kDK;
#pragma unroll
            for (int d = 0; d < kDK; ++d) s = fmaf(qv[d], kr[d], s);
            s *= kScale;
            m = fmaxf(m, s);
        }
        sraw[j] = s;
    }
    m = wave_max64(m);
    float tsum = 0.f;
#pragma unroll
    for (int j = 0; j < 8; ++j) {
        p[j] = (k0 + j < L) ? __expf(sraw[j] - m) : 0.f;
        tsum += p[j];
    }
    const float tot = wave_sum64(tsum);
    const float inv_tot = 1.f / tot;
    float run = 0.f, csum[8];
#pragma unroll
    for (int j = 0; j < 8; ++j) { run += p[j] * inv_tot; csum[j] = run; }
    float inc = run;
#pragma unroll
    for (int off = 1; off < 64; off <<= 1) {
        float t = __shfl_up(inc, off);
        if (lane >= off) inc += t;
    }
    const float excl = inc - run;

    const float gh = -fabsf(gam[h]);
    float s2[8];
    float m2 = -3e38f;
#pragma unroll
    for (int j = 0; j < 8; ++j) {
        const int k = k0 + j;
        s2[j] = 0.f;
        if (k < L) {
            const float rem = 1.f - (excl + csum[j]);
            const float val = fmaxf(rem * (float)(q - k), 0.f);
            const float te = fmaxf(__expf(gh * sqrtf(val)), 1e-5f);
            s2[j] = sraw[j] * te;
            m2 = fmaxf(m2, s2[j]);
        }
    }
    m2 = wave_max64(m2);
    float sum2 = 0.f;
#pragma unroll
    for (int j = 0; j < 8; ++j) {
        p[j] = (k0 + j < L) ? __expf(s2[j] - m2) : 0.f;
        sum2 += p[j];
    }
    sum2 = wave_sum64(sum2);
    const float inv2 = 1.f / sum2;
    float ov[8];
#pragma unroll
    for (int j = 0; j < 8; ++j) {
        const float f = p[j] * inv2;   // maxout=False in block 1
        fs[k0 + j] = f;
        ov[j] = f;
    }
    {
        float* qrow = q_scores + (size_t)rid * kS + k0;
        *(f32x4*)(qrow) = *(f32x4*)(ov);
        *(f32x4*)(qrow + 4) = *(f32x4*)(ov + 4);
    }
    __syncthreads();

    // PV: lanes (d, half) with balanced k split
    const int d = lane & 31;
    const int Lh = (L + 1) >> 1;
    const int kb = (lane & 32) ? Lh : 0;
    const int ke = (lane & 32) ? L : Lh;
    float acc = 0.f;
    for (int k = kb; k < ke; ++k)
        acc = fmaf(fs[k], Vbase[(size_t)k * kDK + d], acc);
    acc += __shfl_xor(acc, 32);
    if (lane < 32) A1[((size_t)bh * kS + q) * kDK + d] = acc;
}

// Block-4 prep: per panel (b,nk,h): raw scores (length S), stabilized exp, prefix sums.
__global__ __launch_bounds__(64) void attn4_prep(const float* __restrict__ Q4,
                                                 const float* __restrict__ K4,
                                                 float* __restrict__ rawP,
                                                 float* __restrict__ CpreP) {
    const int panel = blockIdx.x;        // (b*NK + nk)*H + h
    const int h = panel & (kH - 1);
    const int bnk = panel >> 3;
    const int nk = bnk & (kNK - 1);
    const int b = bnk >> 4;
    const int lane = threadIdx.x;
    const float* Kp = K4 + (size_t)(b * kH + h) * kS * kDK;
    float qv[kDK];
    const float* Qr = Q4 + (size_t)nk * kD + h * kDK;
#pragma unroll
    for (int d = 0; d < kDK; ++d) qv[d] = Qr[d];

    const int k0 = lane * 8;
    float raw[8];
    float m = -3e38f;
#pragma unroll
    for (int j = 0; j < 8; ++j) {
        const float* kr = Kp + (size_t)(k0 + j) * kDK;
        float s = 0.f;
#pragma unroll
        for (int d = 0; d < kDK; ++d) s = fmaf(qv[d], kr[d], s);
        raw[j] = s * kScale;
        m = fmaxf(m, raw[j]);
    }
    m = wave_max64(m);
    float E[8];
    float s = 0.f;
#pragma unroll
    for (int j = 0; j < 8; ++j) { E[j] = __expf(raw[j] - m); s += E[j]; }
    float inc = s;
#pragma unroll
    for (int off = 1; off < 64; off <<= 1) {
        float t = __shfl_up(inc, off);
        if (lane >= off) inc += t;
    }
    float run = inc - s;   // exclusive prefix of lane sums
    float cp[8];
#pragma unroll
    for (int j = 0; j < 8; ++j) { run += E[j]; cp[j] = run; }

    float* rrow = rawP + (size_t)panel * kS + k0;
    float* crow = CpreP + (size_t)panel * kS + k0;
    *(f32x4*)(rrow) = *(f32x4*)(raw);
    *(f32x4*)(rrow + 4) = *(f32x4*)(raw + 4);
    *(f32x4*)(crow) = *(f32x4*)(cp);
    *(f32x4*)(crow + 4) = *(f32x4*)(cp + 4);
}

// Block-4 main: 4 waves/block, one q-row per wave per iteration, no barriers in loop.
__global__ __launch_bounds__(256) void attn4_main(const float* __restrict__ rawP,
                                                  const float* __restrict__ CpreP,
                                                  const float* __restrict__ V4,
                                                  const float* __restrict__ gam,
                                                  float* __restrict__ k_scores,
                                                  float* __restrict__ A4) {
    __shared__ u16 Vlds[kS * kDK];       // 32 KB
    __shared__ float raws[kS];           // 2 KB
    __shared__ float cps[kS];            // 2 KB
    __shared__ float fsb[4][kS];         // 8 KB
    const int panel = blockIdx.x;        // (b*NK + nk)*H + h
    const int q0 = blockIdx.y * 64;
    const int h = panel & (kH - 1);
    const int bnk = panel >> 3;
    const int nk = bnk & (kNK - 1);
    const int b = bnk >> 4;
    const int tid = threadIdx.x;
    const int lane = tid & 63;
    const int w = tid >> 6;

    const float* Vp = V4 + (size_t)(b * kH + h) * kS * kDK;
    for (int i = tid * 4; i < kS * kDK; i += 1024) {
        f32x4 v = *(const f32x4*)(Vp + i);
        u16x4 pk = {f2bf(v[0]), f2bf(v[1]), f2bf(v[2]), f2bf(v[3])};
        *(u16x4*)(Vlds + i) = pk;
    }
    for (int i = tid; i < kS; i += 256) {
        raws[i] = rawP[(size_t)panel * kS + i];
        cps[i] = CpreP[(size_t)panel * kS + i];
    }
    __syncthreads();

    const float gh = -fabsf(gam[h]);
    const int k0 = lane * 8;
    // row-invariant per-lane data
    float rw[8], cp[8];
    *(f32x4*)(rw) = *(const f32x4*)(raws + k0);
    *(f32x4*)(rw + 4) = *(const f32x4*)(raws + k0 + 4);
    *(f32x4*)(cp) = *(const f32x4*)(cps + k0);
    *(f32x4*)(cp + 4) = *(const f32x4*)(cps + k0 + 4);

    float* fw = fsb[w];
    const int d = lane & 31;
    const int half = lane >> 5;

    for (int i = 0; i < 16; ++i) {
        const int q = q0 + w * 16 + i;
        float* krow = k_scores + ((size_t)((b * kH + h) * kS + q) * kNK + nk) * kS;
        float* arow = A4 + ((size_t)panel * kS + q) * kDK;
        const int L = q;                 // strict mask: k < q
        if (L == 0) {
            f32x4 z = {0.f, 0.f, 0.f, 0.f};
            *(f32x4*)(krow + k0) = z;
            *(f32x4*)(krow + k0 + 4) = z;
            if (lane < 32) arow[lane] = 0.f;
            continue;
        }
        const float invCL = 1.f / cps[L - 1];
        float p[8];
        float m2 = -3e38f;
#pragma unroll
        for (int j = 0; j < 8; ++j) {
            const int k = k0 + j;
            float s2 = 0.f;
            if (k < L) {
                const float rem = 1.f - cp[j] * invCL;
                const float val = fmaxf(rem * (float)(L - k), 0.f);
                const float te = fmaxf(__expf(gh * sqrtf(val)), 1e-5f);
                s2 = rw[j] * te;
                m2 = fmaxf(m2, s2);
            }
            p[j] = s2;
        }
        m2 = wave_max64(m2);
        float sum2 = 0.f;
#pragma unroll
        for (int j = 0; j < 8; ++j) {
            p[j] = (k0 + j < L) ? __expf(p[j] - m2) : 0.f;
            sum2 += p[j];
        }
        sum2 = wave_sum64(sum2);
        const float inv2 = 1.f / sum2;
        float mx = 0.f;
#pragma unroll
        for (int j = 0; j < 8; ++j) { p[j] *= inv2; mx = fmaxf(mx, p[j]); }
        mx = wave_max64(mx);
        const float scl = fminf(1.f / mx, 5.f);   // maxout=True
#pragma unroll
        for (int j = 0; j < 8; ++j) p[j] *= scl;
        *(f32x4*)(krow + k0) = *(f32x4*)(p);
        *(f32x4*)(krow + k0 + 4) = *(f32x4*)(p + 4);
        *(f32x4*)(fw + k0) = *(f32x4*)(p);
        *(f32x4*)(fw + k0 + 4) = *(f32x4*)(p + 4);

        // PV: halves split k-range at 4-aligned midpoint; f32x4 fs broadcasts
        int Lh = ((L >> 1) + 3) & ~3;
        if (Lh > L) Lh = L;
        const int kb = half ? Lh : 0;
        const int ke = half ? L : Lh;
        float acc = 0.f;
        int k = kb;
        for (; k + 4 <= ke; k += 4) {
            f32x4 fv = *(const f32x4*)(fw + k);
            const int base = k * kDK + d;
            acc = fmaf(fv[0], bf2f(Vlds[base]), acc);
            acc = fmaf(fv[1], bf2f(Vlds[base + 32]), acc);
            acc = fmaf(fv[2], bf2f(Vlds[base + 64]), acc);
            acc = fmaf(fv[3], bf2f(Vlds[base + 96]), acc);
        }
        for (; k < ke; ++k) acc = fmaf(fw[k], bf2f(Vlds[k * kDK + d]), acc);
        acc += __shfl_xor(acc, 32);
        if (lane < 32) arow[d] = acc;
    }
}

extern "C" void kernel_launch(void* const* d_in, const int* in_sizes, int n_in,
                              void* d_out, int out_size, void* d_ws, size_t ws_size,
                              hipStream_t stream) {
    (void)in_sizes; (void)n_in; (void)out_size; (void)ws_size;

    const float* q_emb = (const float*)d_in[0];
    const float* s_emb = (const float*)d_in[1];
    // d_in[2]=s_emb_extr, d_in[3]=lens, d_in[4]=at : unused by reference
    const float* Wq1 = (const float*)d_in[5];  const float* bq1 = (const float*)d_in[6];
    const float* Wv1 = (const float*)d_in[7];  const float* bv1 = (const float*)d_in[8];
    const float* Wo1 = (const float*)d_in[9];  const float* bo1 = (const float*)d_in[10];
    const float* gam1 = (const float*)d_in[11];
    const float* ln1g = (const float*)d_in[12]; const float* ln1b = (const float*)d_in[13];
    const float* Wq4 = (const float*)d_in[14]; const float* bq4 = (const float*)d_in[15];
    const float* Wk4 = (const float*)d_in[16]; const float* bk4 = (const float*)d_in[17];
    const float* Wv4 = (const float*)d_in[18]; const float* bv4 = (const float*)d_in[19];
    const float* Wo4 = (const float*)d_in[20]; const float* bo4 = (const float*)d_in[21];
    const float* gam4 = (const float*)d_in[22];
    const float* ln4g = (const float*)d_in[23]; const float* ln4b = (const float*)d_in[24];
    const float* know = (const float*)d_in[25];

    float* ws = (float*)d_ws;
    const size_t NBHSD = (size_t)kB * kH * kS * kDK;       // 262144
    float* Q1 = ws;
    float* V1 = Q1 + NBHSD;                                 // freed after attn1 -> rawP/CpreP
    float* A1 = V1 + NBHSD;
    float* P  = A1 + NBHSD;
    float* K4 = P  + (size_t)kB * kS * kD;
    float* V4 = K4 + NBHSD;
    float* Q4 = V4 + NBHSD;                                 // NK*D = 4096
    float* A4 = Q4 + (size_t)kNK * kD;                      // B*NK*H*S*DK = 4194304
    float* WT = A4 + (size_t)kB * kNK * kH * kS * kDK;      // 6 * 65536 floats

    float* rawP = V1;                                       // 131072 floats
    float* CpreP = V1 + (size_t)kB * kNK * kH * kS;         // 131072 floats

    float* WTq1 = WT + 0 * (size_t)kD * kD;
    float* WTv1 = WT + 1 * (size_t)kD * kD;
    float* WTo1 = WT + 2 * (size_t)kD * kD;
    float* WTk4 = WT + 3 * (size_t)kD * kD;
    float* WTv4 = WT + 4 * (size_t)kD * kD;
    float* WTo4 = WT + 5 * (size_t)kD * kD;

    float* zout = (float*)d_out;                            // (B,S,NK*D)
    float* q_scores = zout + (size_t)kB * kS * kNK * kD;    // (B,H,S,S)
    float* k_scores = q_scores + (size_t)kB * kH * kS * kS; // (B,H,S,NK,S)

    // Weight transposes (once per launch; cheap)
    {
        dim3 g(kD, 6);
        wt_kernel<<<g, 256, 0, stream>>>(Wq1, Wv1, Wo1, Wk4, Wv4, Wo4, WT);
    }

    // Block 1
    gemm256<2, 0><<<kB * kS / 8, 256, 0, stream>>>(q_emb, WTq1, bq1, nullptr, nullptr, nullptr, Q1);
    gemm256<2, 0><<<kB * kS / 8, 256, 0, stream>>>(s_emb, WTv1, bv1, nullptr, nullptr, nullptr, V1);
    attn1_kernel<<<kB * kH * kS, 64, 0, stream>>>(Q1, V1, gam1, q_scores, A1);
    gemm256<2, 1><<<kB * kS / 8, 256, 0, stream>>>(A1, WTo1, bo1, q_emb, ln1g, ln1b, P);

    // Block 4 projections (V1 dead from here; reused as rawP/CpreP)
    gemm256<2, 0><<<kB * kS / 8, 256, 0, stream>>>(q_emb, WTk4, bk4, nullptr, nullptr, nullptr, K4);
    gemm256<2, 0><<<kB * kS / 8, 256, 0, stream>>>(P, WTv4, bv4, nullptr, nullptr, nullptr, V4);
    proj_kernel<<<kNK, 256, 0, stream>>>(know, Wq4, bq4, Q4, 0);

    // Block 4 attention
    attn4_prep<<<kB * kNK * kH, 64, 0, stream>>>(Q4, K4, rawP, CpreP);
    dim3 g5(kB * kNK * kH, kS / 64);
    attn4_main<<<g5, 256, 0, stream>>>(rawP, CpreP, V4, gam4, k_scores, A4);

    // Block 4 epilogue (tiled GEMM + LN + scatter)
    gemm256<8, 2><<<kB * kNK * kS / 32, 256, 0, stream>>>(A4, WTo4, bo4, know, ln4g, ln4b, zout);
}

// Round 5
// 424.938 us; speedup vs baseline: 5.3503x; 1.2088x over previous
//
#include <hip/hip_runtime.h>

// DTransformer forward (f32 in/out, f32 internal)
// B=2 S=512 D=256 H=8 DK=32 NK=16

namespace {
constexpr int kB = 2, kS = 512, kD = 256, kH = 8, kDK = 32, kNK = 16;
constexpr float kScale = 0.17677669529663687f;  // 1/sqrt(32)
constexpr int kPS = 520;                        // padded LDS row stride (bf16 elems)
}

typedef unsigned short u16;
typedef u16 u16x4 __attribute__((ext_vector_type(4)));
typedef u16 u16x8 __attribute__((ext_vector_type(8)));
typedef short s16x8 __attribute__((ext_vector_type(8)));
typedef float f32x4 __attribute__((ext_vector_type(4)));

__device__ __forceinline__ float bf2f(u16 u) { return __uint_as_float(((unsigned)u) << 16); }
__device__ __forceinline__ u16 f2bf(float f) {
    unsigned u = __float_as_uint(f);
    return (u16)((u + 0x7fffu + ((u >> 16) & 1u)) >> 16);
}

__device__ __forceinline__ float wave_max64(float v) {
#pragma unroll
    for (int off = 32; off; off >>= 1) v = fmaxf(v, __shfl_xor(v, off));
    return v;
}
__device__ __forceinline__ float wave_sum64(float v) {
#pragma unroll
    for (int off = 32; off; off >>= 1) v += __shfl_xor(v, off);
    return v;
}

// Transpose 6 weight matrices [c][k] -> [k][c] (256x256 each)
__global__ __launch_bounds__(256) void wt_kernel(const float* __restrict__ W0,
                                                 const float* __restrict__ W1,
                                                 const float* __restrict__ W2,
                                                 const float* __restrict__ W3,
                                                 const float* __restrict__ W4,
                                                 const float* __restrict__ W5,
                                                 float* __restrict__ WT) {
    const float* srcs[6] = {W0, W1, W2, W3, W4, W5};
    const float* W = srcs[blockIdx.y];
    float* T = WT + (size_t)blockIdx.y * kD * kD;
    const int k = blockIdx.x, c = threadIdx.x;
    T[(size_t)k * kD + c] = W[(size_t)c * kD + k];
}

// Unified tiled GEMM: Y[row,c] = sum_k X[row,k]*W[c,k] + bias[c], W given transposed.
// MODE 0: X plain [row][256], Y scattered to [(row>>9)*8+h][s][dk]
// MODE 1: X gathered from A-layout, +extra[row][c] residual, LN, Y plain [row][256]
// MODE 2: X gathered from A-layout, +extra[nk][c], LN, Y scattered to [(b,s,nk)][c]
template <int RPW, int MODE>
__global__ __launch_bounds__(256) void gemm256(const float* __restrict__ X,
                                               const float* __restrict__ WT,
                                               const float* __restrict__ bias,
                                               const float* __restrict__ extra,
                                               const float* __restrict__ lng,
                                               const float* __restrict__ lnb,
                                               float* __restrict__ Y) {
    constexpr int TM = RPW * 4;
    __shared__ float xs[TM][kD];
    const int t = threadIdx.x;
    const int r0 = blockIdx.x * TM;

    if (MODE == 0) {
#pragma unroll
        for (int it = 0; it < RPW; ++it) {
            const int idx = it * 1024 + t * 4;
            const int r = idx >> 8, c = idx & 255;
            *(f32x4*)&xs[r][c] = *(const f32x4*)(X + (size_t)(r0 + r) * kD + c);
        }
    } else {
#pragma unroll
        for (int it = 0; it < RPW; ++it) {
            const int chunk = it * 32 + (t >> 3);   // 0..TM*8-1
            const int r = chunk >> 3, h = chunk & 7;
            const int row = r0 + r;
            const float* src = X + (((size_t)(row >> 9) * kH + h) * kS + (row & (kS - 1))) * kDK + (t & 7) * 4;
            *(f32x4*)&xs[r][h * kDK + (t & 7) * 4] = *(const f32x4*)src;
        }
    }
    __syncthreads();

    const int wv = t >> 6;
    const int c4 = (t & 63) * 4;
    float acc[RPW][4];
    {
        f32x4 bv = *(const f32x4*)(bias + c4);
#pragma unroll
        for (int r = 0; r < RPW; ++r)
#pragma unroll
            for (int j = 0; j < 4; ++j) acc[r][j] = bv[j];
    }
    for (int k0 = 0; k0 < kD; k0 += 4) {
        f32x4 w0 = *(const f32x4*)(WT + (size_t)(k0 + 0) * kD + c4);
        f32x4 w1 = *(const f32x4*)(WT + (size_t)(k0 + 1) * kD + c4);
        f32x4 w2 = *(const f32x4*)(WT + (size_t)(k0 + 2) * kD + c4);
        f32x4 w3 = *(const f32x4*)(WT + (size_t)(k0 + 3) * kD + c4);
#pragma unroll
        for (int r = 0; r < RPW; ++r) {
            f32x4 xv = *(const f32x4*)&xs[wv * RPW + r][k0];
#pragma unroll
            for (int cc = 0; cc < 4; ++cc) {
                acc[r][cc] = fmaf(xv[0], w0[cc], acc[r][cc]);
                acc[r][cc] = fmaf(xv[1], w1[cc], acc[r][cc]);
                acc[r][cc] = fmaf(xv[2], w2[cc], acc[r][cc]);
                acc[r][cc] = fmaf(xv[3], w3[cc], acc[r][cc]);
            }
        }
    }

#pragma unroll
    for (int r = 0; r < RPW; ++r) {
        const int row = r0 + wv * RPW + r;
        if (MODE == 0) {
            const int h = c4 >> 5, dk = c4 & 31;
            *(f32x4*)(Y + (((size_t)(row >> 9) * kH + h) * kS + (row & (kS - 1))) * kDK + dk) =
                *(f32x4*)acc[r];
        } else {
            f32x4 x;
            if (MODE == 1) {
                f32x4 e = *(const f32x4*)(extra + (size_t)row * kD + c4);
#pragma unroll
                for (int j = 0; j < 4; ++j) x[j] = acc[r][j] + e[j];
            } else {
                const int nk = (row >> 9) & (kNK - 1);
                f32x4 e = *(const f32x4*)(extra + (size_t)nk * kD + c4);
#pragma unroll
                for (int j = 0; j < 4; ++j) x[j] = acc[r][j] + e[j];
            }
            float s1 = x[0] + x[1] + x[2] + x[3];
            float s2 = x[0] * x[0] + x[1] * x[1] + x[2] * x[2] + x[3] * x[3];
#pragma unroll
            for (int off = 32; off; off >>= 1) {
                s1 += __shfl_xor(s1, off);
                s2 += __shfl_xor(s2, off);
            }
            const float mean = s1 * (1.f / kD);
            const float var = s2 * (1.f / kD) - mean * mean;
            const float rstd = rsqrtf(var + 1e-5f);
            f32x4 g = *(const f32x4*)(lng + c4);
            f32x4 bb = *(const f32x4*)(lnb + c4);
            f32x4 y;
#pragma unroll
            for (int j = 0; j < 4; ++j) y[j] = (x[j] - mean) * rstd * g[j] + bb[j];
            if (MODE == 1) {
                *(f32x4*)(Y + (size_t)row * kD + c4) = y;
            } else {
                const int bnk = row >> 9, s = row & (kS - 1);
                const int nk = bnk & (kNK - 1), b = bnk >> 4;
                *(f32x4*)(Y + (((size_t)(b * kS + s) * kNK + nk) * kD) + c4) = y;
            }
        }
    }
}

// one-row-per-block projection (kept only for tiny Q4: 16 rows)
__global__ __launch_bounds__(256) void proj_kernel(const float* __restrict__ X,
                                                   const float* __restrict__ W,
                                                   const float* __restrict__ bias,
                                                   float* __restrict__ Y, int scatter) {
    const int row = blockIdx.x;
    const int c = threadIdx.x;
    __shared__ float xs[kD];
    xs[c] = X[(size_t)row * kD + c];
    __syncthreads();
    float acc = bias[c];
    const float* wr = W + (size_t)c * kD;
#pragma unroll 4
    for (int k0 = 0; k0 < kD; k0 += 4) {
        f32x4 wv = *(const f32x4*)(wr + k0);
#pragma unroll
        for (int j = 0; j < 4; ++j) acc = fmaf(xs[k0 + j], wv[j], acc);
    }
    if (scatter) {
        const int b = row >> 9, s = row & (kS - 1);
        const int h = c >> 5, dk = c & 31;
        Y[((size_t)(b * kH + h) * kS + s) * kDK + dk] = acc;
    } else {
        Y[(size_t)row * kD + c] = acc;
    }
}

// Block-1 attention: one wave per (b,h,q) row. K == Q (shared proj).
__global__ __launch_bounds__(64) void attn1_kernel(const float* __restrict__ Q1,
                                                   const float* __restrict__ V1,
                                                   const float* __restrict__ gam,
                                                   float* __restrict__ q_scores,
                                                   float* __restrict__ A1) {
    __shared__ float fs[kS];
    const int rid = blockIdx.x;          // (b*H + h)*S + q
    const int q = rid & (kS - 1);
    const int bh = rid >> 9;
    const int h = bh & (kH - 1);
    const int lane = threadIdx.x;
    const float* Kbase = Q1 + (size_t)bh * kS * kDK;
    const float* Vbase = V1 + (size_t)bh * kS * kDK;
    float qv[kDK];
#pragma unroll
    for (int d = 0; d < kDK; ++d) qv[d] = Kbase[(size_t)q * kDK + d];
    const int L = q + 1;                 // peek_cur: k <= q
    const int k0 = lane * 8;

    float sraw[8], p[8];
    float m = -3e38f;
#pragma unroll
    for (int j = 0; j < 8; ++j) {
        const int k = k0 + j;
        float s = 0.f;
        if (k < L) {
            const float* kr = Kbase + (size_t)k * kDK;
#pragma unroll
            for (int d = 0; d < kDK; ++d) s = fmaf(qv[d], kr[d], s);
            s *= kScale;
            m = fmaxf(m, s);
        }
        sraw[j] = s;
    }
    m = wave_max64(m);
    float tsum = 0.f;
#pragma unroll
    for (int j = 0; j < 8; ++j) {
        p[j] = (k0 + j < L) ? __expf(sraw[j] - m) : 0.f;
        tsum += p[j];
    }
    const float tot = wave_sum64(tsum);
    const float inv_tot = 1.f / tot;
    float run = 0.f, csum[8];
#pragma unroll
    for (int j = 0; j < 8; ++j) { run += p[j] * inv_tot; csum[j] = run; }
    float inc = run;
#pragma unroll
    for (int off = 1; off < 64; off <<= 1) {
        float t = __shfl_up(inc, off);
        if (lane >= off) inc += t;
    }
    const float excl = inc - run;

    const float gh = -fabsf(gam[h]);
    float s2[8];
    float m2 = -3e38f;
#pragma unroll
    for (int j = 0; j < 8; ++j) {
        const int k = k0 + j;
        s2[j] = 0.f;
        if (k < L) {
            const float rem = 1.f - (excl + csum[j]);
            const float val = fmaxf(rem * (float)(q - k), 0.f);
            const float te = fmaxf(__expf(gh * sqrtf(val)), 1e-5f);
            s2[j] = sraw[j] * te;
            m2 = fmaxf(m2, s2[j]);
        }
    }
    m2 = wave_max64(m2);
    float sum2 = 0.f;
#pragma unroll
    for (int j = 0; j < 8; ++j) {
        p[j] = (k0 + j < L) ? __expf(s2[j] - m2) : 0.f;
        sum2 += p[j];
    }
    sum2 = wave_sum64(sum2);
    const float inv2 = 1.f / sum2;
    float ov[8];
#pragma unroll
    for (int j = 0; j < 8; ++j) {
        const float f = p[j] * inv2;   // maxout=False in block 1
        fs[k0 + j] = f;
        ov[j] = f;
    }
    {
        float* qrow = q_scores + (size_t)rid * kS + k0;
        *(f32x4*)(qrow) = *(f32x4*)(ov);
        *(f32x4*)(qrow + 4) = *(f32x4*)(ov + 4);
    }
    __syncthreads();

    // PV: lanes (d, half) with balanced k split
    const int d = lane & 31;
    const int Lh = (L + 1) >> 1;
    const int kb = (lane & 32) ? Lh : 0;
    const int ke = (lane & 32) ? L : Lh;
    float acc = 0.f;
    for (int k = kb; k < ke; ++k)
        acc = fmaf(fs[k], Vbase[(size_t)k * kDK + d], acc);
    acc += __shfl_xor(acc, 32);
    if (lane < 32) A1[((size_t)bh * kS + q) * kDK + d] = acc;
}

// Block-4 prep: per panel (b,nk,h): raw scores (length S), stabilized exp, prefix sums.
__global__ __launch_bounds__(64) void attn4_prep(const float* __restrict__ Q4,
                                                 const float* __restrict__ K4,
                                                 float* __restrict__ rawP,
                                                 float* __restrict__ CpreP) {
    const int panel = blockIdx.x;        // (b*NK + nk)*H + h
    const int h = panel & (kH - 1);
    const int bnk = panel >> 3;
    const int nk = bnk & (kNK - 1);
    const int b = bnk >> 4;
    const int lane = threadIdx.x;
    const float* Kp = K4 + (size_t)(b * kH + h) * kS * kDK;
    float qv[kDK];
    const float* Qr = Q4 + (size_t)nk * kD + h * kDK;
#pragma unroll
    for (int d = 0; d < kDK; ++d) qv[d] = Qr[d];

    const int k0 = lane * 8;
    float raw[8];
    float m = -3e38f;
#pragma unroll
    for (int j = 0; j < 8; ++j) {
        const float* kr = Kp + (size_t)(k0 + j) * kDK;
        float s = 0.f;
#pragma unroll
        for (int d = 0; d < kDK; ++d) s = fmaf(qv[d], kr[d], s);
        raw[j] = s * kScale;
        m = fmaxf(m, raw[j]);
    }
    m = wave_max64(m);
    float E[8];
    float s = 0.f;
#pragma unroll
    for (int j = 0; j < 8; ++j) { E[j] = __expf(raw[j] - m); s += E[j]; }
    float inc = s;
#pragma unroll
    for (int off = 1; off < 64; off <<= 1) {
        float t = __shfl_up(inc, off);
        if (lane >= off) inc += t;
    }
    float run = inc - s;   // exclusive prefix of lane sums
    float cp[8];
#pragma unroll
    for (int j = 0; j < 8; ++j) { run += E[j]; cp[j] = run; }

    float* rrow = rawP + (size_t)panel * kS + k0;
    float* crow = CpreP + (size_t)panel * kS + k0;
    *(f32x4*)(rrow) = *(f32x4*)(raw);
    *(f32x4*)(rrow + 4) = *(f32x4*)(raw + 4);
    *(f32x4*)(crow) = *(f32x4*)(cp);
    *(f32x4*)(crow + 4) = *(f32x4*)(cp + 4);
}

// Block-4 main v2: 32 q-rows per block, 4 waves.
// Phase 1 (row-per-lane online softmax stats), Phase 2 (k-on-lanes write pass),
// Phase 3 (MFMA PV: O[32x32] = P[32x512] * V[512x32] in bf16).
__global__ __launch_bounds__(256) void attn4_main(const float* __restrict__ rawP,
                                                  const float* __restrict__ CpreP,
                                                  const float* __restrict__ V4,
                                                  const float* __restrict__ gam,
                                                  float* __restrict__ k_scores,
                                                  float* __restrict__ A4) {
    extern __shared__ char smem[];
    u16* Vt = (u16*)smem;                        // [32][kPS] bf16 (V transposed)
    u16* Pl = (u16*)(smem + 32 * kPS * 2);       // [32][kPS] bf16 (P rows)
    float* raws_l = (float*)(smem + 2 * 32 * kPS * 2);  // [512]
    float* cps_l = raws_l + kS;                  // [512]

    const int panel = blockIdx.x;        // (b*NK + nk)*H + h
    const int q0 = blockIdx.y * 32;
    const int h = panel & (kH - 1);
    const int bnk = panel >> 3;
    const int nk = bnk & (kNK - 1);
    const int b = bnk >> 4;
    const int tid = threadIdx.x;
    const int lane = tid & 63;
    const int w = tid >> 6;

    // Stage V transposed (bf16) and raw/cp vectors
    const float* Vp = V4 + (size_t)(b * kH + h) * kS * kDK;
    for (int idx = tid * 4; idx < kS * kDK; idx += 1024) {
        const int k = idx >> 5, d = idx & 31;
        f32x4 v = *(const f32x4*)(Vp + idx);
        Vt[(d + 0) * kPS + k] = f2bf(v[0]);
        Vt[(d + 1) * kPS + k] = f2bf(v[1]);
        Vt[(d + 2) * kPS + k] = f2bf(v[2]);
        Vt[(d + 3) * kPS + k] = f2bf(v[3]);
    }
    for (int i = tid; i < kS; i += 256) {
        raws_l[i] = rawP[(size_t)panel * kS + i];
        cps_l[i] = CpreP[(size_t)panel * kS + i];
    }
    __syncthreads();

    const float gh = -fabsf(gam[h]);
    const int rbase = w * 8;

    // Phase 1: online softmax stats; lane -> (row = rbase + (lane&7), k-subgroup = lane>>3)
    const int lrow = rbase + (lane & 7);
    const int sub = lane >> 3;
    const int Lq = q0 + lrow;            // strict mask: k < Lq
    const float invCL = 1.f / cps_l[(Lq > 0 ? Lq : 1) - 1];
    float m2 = -3e38f, sum2 = 0.f;
    for (int ks = 0; ks < 64; ++ks) {
        const int k = ks * 8 + sub;
        const float rawk = raws_l[k];
        const float cpk = cps_l[k];
        const bool ok = (k < Lq);
        const float rem = 1.f - cpk * invCL;
        const float val = fmaxf(rem * (float)(Lq - k), 0.f);
        const float te = fmaxf(__expf(gh * sqrtf(val)), 1e-5f);
        const float s2 = rawk * te;
        const float mn = ok ? fmaxf(m2, s2) : m2;
        const float c = ok ? __expf(s2 - mn) : 0.f;
        sum2 = sum2 * __expf(m2 - mn) + c;
        m2 = mn;
    }
#pragma unroll
    for (int off = 8; off < 64; off <<= 1) {
        const float mo = __shfl_xor(m2, off);
        const float so = __shfl_xor(sum2, off);
        const float mn = fmaxf(m2, mo);
        sum2 = sum2 * __expf(m2 - mn) + so * __expf(mo - mn);
        m2 = mn;
    }
    // maxout: max_k p = 1/sum2  =>  scale = min(sum2,5)/sum2 folded into p
    const float scl = fminf(sum2, 5.f) / sum2;

    // Phase 2: k-on-lanes, rows serial; write k_scores (f32, coalesced) + Pl (bf16)
    const int k0 = lane * 8;
    float rw[8], cp[8];
    *(f32x4*)(rw) = *(const f32x4*)(raws_l + k0);
    *(f32x4*)(rw + 4) = *(const f32x4*)(raws_l + k0 + 4);
    *(f32x4*)(cp) = *(const f32x4*)(cps_l + k0);
    *(f32x4*)(cp + 4) = *(const f32x4*)(cps_l + k0 + 4);

    for (int r = 0; r < 8; ++r) {
        const int row = rbase + r;
        const int Lr = q0 + row;
        const float m2r = __shfl(m2, r);
        const float sclr = __shfl(scl, r);
        const float invr = __shfl(invCL, r);
        float pf[8];
        u16x8 pb;
#pragma unroll
        for (int j = 0; j < 8; ++j) {
            const int k = k0 + j;
            const float rem = 1.f - cp[j] * invr;
            const float val = fmaxf(rem * (float)(Lr - k), 0.f);
            const float te = fmaxf(__expf(gh * sqrtf(val)), 1e-5f);
            const float s2 = rw[j] * te;
            const float p = (k < Lr) ? __expf(s2 - m2r) * sclr : 0.f;
            pf[j] = p;
            pb[j] = f2bf(p);
        }
        float* krow = k_scores + ((size_t)((b * kH + h) * kS + Lr) * kNK + nk) * kS;
        *(f32x4*)(krow + k0) = *(f32x4*)(pf);
        *(f32x4*)(krow + k0 + 4) = *(f32x4*)(pf + 4);
        *(u16x8*)(Pl + (size_t)row * kPS + k0) = pb;
    }
    __syncthreads();

    // Phase 3: MFMA PV. wave w: rows 16*(w&1).., dims 16*(w>>1)..
    const int rowblk = (w & 1) * 16;
    const int dblk = (w >> 1) * 16;
    const u16* Arow = Pl + (size_t)(rowblk + (lane & 15)) * kPS + (lane >> 4) * 8;
    const u16* Brow = Vt + (size_t)(dblk + (lane & 15)) * kPS + (lane >> 4) * 8;
    f32x4 acc = {0.f, 0.f, 0.f, 0.f};
#pragma unroll
    for (int kc = 0; kc < kS; kc += 32) {
        s16x8 a = *(const s16x8*)(Arow + kc);
        s16x8 bfr = *(const s16x8*)(Brow + kc);
        acc = __builtin_amdgcn_mfma_f32_16x16x32_bf16(a, bfr, acc, 0, 0, 0);
    }
    const int d = dblk + (lane & 15);
#pragma unroll
    for (int j = 0; j < 4; ++j) {
        const int row = rowblk + (lane >> 4) * 4 + j;
        A4[((size_t)panel * kS + (q0 + row)) * kDK + d] = acc[j];
    }
}

extern "C" void kernel_launch(void* const* d_in, const int* in_sizes, int n_in,
                              void* d_out, int out_size, void* d_ws, size_t ws_size,
                              hipStream_t stream) {
    (void)in_sizes; (void)n_in; (void)out_size; (void)ws_size;

    const float* q_emb = (const float*)d_in[0];
    const float* s_emb = (const float*)d_in[1];
    // d_in[2]=s_emb_extr, d_in[3]=lens, d_in[4]=at : unused by reference
    const float* Wq1 = (const float*)d_in[5];  const float* bq1 = (const float*)d_in[6];
    const float* Wv1 = (const float*)d_in[7];  const float* bv1 = (const float*)d_in[8];
    const float* Wo1 = (const float*)d_in[9];  const float* bo1 = (const float*)d_in[10];
    const float* gam1 = (const float*)d_in[11];
    const float* ln1g = (const float*)d_in[12]; const float* ln1b = (const float*)d_in[13];
    const float* Wq4 = (const float*)d_in[14]; const float* bq4 = (const float*)d_in[15];
    const float* Wk4 = (const float*)d_in[16]; const float* bk4 = (const float*)d_in[17];
    const float* Wv4 = (const float*)d_in[18]; const float* bv4 = (const float*)d_in[19];
    const float* Wo4 = (const float*)d_in[20]; const float* bo4 = (const float*)d_in[21];
    const float* gam4 = (const float*)d_in[22];
    const float* ln4g = (const float*)d_in[23]; const float* ln4b = (const float*)d_in[24];
    const float* know = (const float*)d_in[25];

    float* ws = (float*)d_ws;
    const size_t NBHSD = (size_t)kB * kH * kS * kDK;       // 262144
    float* Q1 = ws;
    float* V1 = Q1 + NBHSD;                                 // freed after attn1 -> rawP/CpreP
    float* A1 = V1 + NBHSD;
    float* P  = A1 + NBHSD;
    float* K4 = P  + (size_t)kB * kS * kD;
    float* V4 = K4 + NBHSD;
    float* Q4 = V4 + NBHSD;                                 // NK*D = 4096
    float* A4 = Q4 + (size_t)kNK * kD;                      // B*NK*H*S*DK = 4194304
    float* WT = A4 + (size_t)kB * kNK * kH * kS * kDK;      // 6 * 65536 floats

    float* rawP = V1;                                       // 131072 floats
    float* CpreP = V1 + (size_t)kB * kNK * kH * kS;         // 131072 floats

    float* WTq1 = WT + 0 * (size_t)kD * kD;
    float* WTv1 = WT + 1 * (size_t)kD * kD;
    float* WTo1 = WT + 2 * (size_t)kD * kD;
    float* WTk4 = WT + 3 * (size_t)kD * kD;
    float* WTv4 = WT + 4 * (size_t)kD * kD;
    float* WTo4 = WT + 5 * (size_t)kD * kD;

    float* zout = (float*)d_out;                            // (B,S,NK*D)
    float* q_scores = zout + (size_t)kB * kS * kNK * kD;    // (B,H,S,S)
    float* k_scores = q_scores + (size_t)kB * kH * kS * kS; // (B,H,S,NK,S)

    // Weight transposes (once per launch; cheap)
    {
        dim3 g(kD, 6);
        wt_kernel<<<g, 256, 0, stream>>>(Wq1, Wv1, Wo1, Wk4, Wv4, Wo4, WT);
    }

    // Block 1
    gemm256<2, 0><<<kB * kS / 8, 256, 0, stream>>>(q_emb, WTq1, bq1, nullptr, nullptr, nullptr, Q1);
    gemm256<2, 0><<<kB * kS / 8, 256, 0, stream>>>(s_emb, WTv1, bv1, nullptr, nullptr, nullptr, V1);
    attn1_kernel<<<kB * kH * kS, 64, 0, stream>>>(Q1, V1, gam1, q_scores, A1);
    gemm256<2, 1><<<kB * kS / 8, 256, 0, stream>>>(A1, WTo1, bo1, q_emb, ln1g, ln1b, P);

    // Block 4 projections (V1 dead from here; reused as rawP/CpreP)
    gemm256<2, 0><<<kB * kS / 8, 256, 0, stream>>>(q_emb, WTk4, bk4, nullptr, nullptr, nullptr, K4);
    gemm256<2, 0><<<kB * kS / 8, 256, 0, stream>>>(P, WTv4, bv4, nullptr, nullptr, nullptr, V4);
    proj_kernel<<<kNK, 256, 0, stream>>>(know, Wq4, bq4, Q4, 0);

    // Block 4 attention
    attn4_prep<<<kB * kNK * kH, 64, 0, stream>>>(Q4, K4, rawP, CpreP);
    {
        dim3 g5(kB * kNK * kH, kS / 32);
        const int lds_bytes = 2 * 32 * kPS * 2 + 2 * kS * 4;  // Vt + Pl + raws + cps = 70656
        attn4_main<<<g5, 256, lds_bytes, stream>>>(rawP, CpreP, V4, gam4, k_scores, A4);
    }

    // Block 4 epilogue (tiled GEMM + LN + scatter)
    gemm256<8, 2><<<kB * kNK * kS / 32, 256, 0, stream>>>(A4, WTo4, bo4, know, ln4g, ln4b, zout);
}

// Round 6
// 335.964 us; speedup vs baseline: 6.7672x; 1.2648x over previous
//
#include <hip/hip_runtime.h>

// DTransformer forward (f32 in/out, f32 internal)
// B=2 S=512 D=256 H=8 DK=32 NK=16

namespace {
constexpr int kB = 2, kS = 512, kD = 256, kH = 8, kDK = 32, kNK = 16;
constexpr float kScale = 0.17677669529663687f;  // 1/sqrt(32)
constexpr int kPS = 520;                        // padded LDS row stride (bf16 elems)
}

typedef unsigned short u16;
typedef u16 u16x4 __attribute__((ext_vector_type(4)));
typedef u16 u16x8 __attribute__((ext_vector_type(8)));
typedef short s16x8 __attribute__((ext_vector_type(8)));
typedef float f32x4 __attribute__((ext_vector_type(4)));

__device__ __forceinline__ float bf2f(u16 u) { return __uint_as_float(((unsigned)u) << 16); }
__device__ __forceinline__ u16 f2bf(float f) {
    unsigned u = __float_as_uint(f);
    return (u16)((u + 0x7fffu + ((u >> 16) & 1u)) >> 16);
}

__device__ __forceinline__ float wave_max64(float v) {
#pragma unroll
    for (int off = 32; off; off >>= 1) v = fmaxf(v, __shfl_xor(v, off));
    return v;
}

// Transpose 6 weight matrices [c][k] -> [k][c] (256x256 each)
__global__ __launch_bounds__(256) void wt_kernel(const float* __restrict__ W0,
                                                 const float* __restrict__ W1,
                                                 const float* __restrict__ W2,
                                                 const float* __restrict__ W3,
                                                 const float* __restrict__ W4,
                                                 const float* __restrict__ W5,
                                                 float* __restrict__ WT) {
    const float* srcs[6] = {W0, W1, W2, W3, W4, W5};
    const float* W = srcs[blockIdx.y];
    float* T = WT + (size_t)blockIdx.y * kD * kD;
    const int k = blockIdx.x, c = threadIdx.x;
    T[(size_t)k * kD + c] = W[(size_t)c * kD + k];
}

// Unified tiled GEMM: Y[row,c] = sum_k X[row,k]*W[c,k] + bias[c], W given transposed.
// MODE 0: X plain [row][256], Y scattered to [(row>>9)*8+h][s][dk]
// MODE 1: X gathered from A-layout, +extra[row][c] residual, LN, Y plain [row][256]
// MODE 2: X gathered from A-layout, +extra[nk][c], LN, Y scattered to [(b,s,nk)][c]
template <int RPW, int MODE>
__global__ __launch_bounds__(256) void gemm256(const float* __restrict__ X,
                                               const float* __restrict__ WT,
                                               const float* __restrict__ bias,
                                               const float* __restrict__ extra,
                                               const float* __restrict__ lng,
                                               const float* __restrict__ lnb,
                                               float* __restrict__ Y) {
    constexpr int TM = RPW * 4;
    __shared__ float xs[TM][kD];
    const int t = threadIdx.x;
    const int r0 = blockIdx.x * TM;

    if (MODE == 0) {
#pragma unroll
        for (int it = 0; it < RPW; ++it) {
            const int idx = it * 1024 + t * 4;
            const int r = idx >> 8, c = idx & 255;
            *(f32x4*)&xs[r][c] = *(const f32x4*)(X + (size_t)(r0 + r) * kD + c);
        }
    } else {
#pragma unroll
        for (int it = 0; it < RPW; ++it) {
            const int chunk = it * 32 + (t >> 3);   // 0..TM*8-1
            const int r = chunk >> 3, h = chunk & 7;
            const int row = r0 + r;
            const float* src = X + (((size_t)(row >> 9) * kH + h) * kS + (row & (kS - 1))) * kDK + (t & 7) * 4;
            *(f32x4*)&xs[r][h * kDK + (t & 7) * 4] = *(const f32x4*)src;
        }
    }
    __syncthreads();

    const int wv = t >> 6;
    const int c4 = (t & 63) * 4;
    float acc[RPW][4];
    {
        f32x4 bv = *(const f32x4*)(bias + c4);
#pragma unroll
        for (int r = 0; r < RPW; ++r)
#pragma unroll
            for (int j = 0; j < 4; ++j) acc[r][j] = bv[j];
    }
    for (int k0 = 0; k0 < kD; k0 += 4) {
        f32x4 w0 = *(const f32x4*)(WT + (size_t)(k0 + 0) * kD + c4);
        f32x4 w1 = *(const f32x4*)(WT + (size_t)(k0 + 1) * kD + c4);
        f32x4 w2 = *(const f32x4*)(WT + (size_t)(k0 + 2) * kD + c4);
        f32x4 w3 = *(const f32x4*)(WT + (size_t)(k0 + 3) * kD + c4);
#pragma unroll
        for (int r = 0; r < RPW; ++r) {
            f32x4 xv = *(const f32x4*)&xs[wv * RPW + r][k0];
#pragma unroll
            for (int cc = 0; cc < 4; ++cc) {
                acc[r][cc] = fmaf(xv[0], w0[cc], acc[r][cc]);
                acc[r][cc] = fmaf(xv[1], w1[cc], acc[r][cc]);
                acc[r][cc] = fmaf(xv[2], w2[cc], acc[r][cc]);
                acc[r][cc] = fmaf(xv[3], w3[cc], acc[r][cc]);
            }
        }
    }

#pragma unroll
    for (int r = 0; r < RPW; ++r) {
        const int row = r0 + wv * RPW + r;
        if (MODE == 0) {
            const int h = c4 >> 5, dk = c4 & 31;
            *(f32x4*)(Y + (((size_t)(row >> 9) * kH + h) * kS + (row & (kS - 1))) * kDK + dk) =
                *(f32x4*)acc[r];
        } else {
            f32x4 x;
            if (MODE == 1) {
                f32x4 e = *(const f32x4*)(extra + (size_t)row * kD + c4);
#pragma unroll
                for (int j = 0; j < 4; ++j) x[j] = acc[r][j] + e[j];
            } else {
                const int nk = (row >> 9) & (kNK - 1);
                f32x4 e = *(const f32x4*)(extra + (size_t)nk * kD + c4);
#pragma unroll
                for (int j = 0; j < 4; ++j) x[j] = acc[r][j] + e[j];
            }
            float s1 = x[0] + x[1] + x[2] + x[3];
            float s2 = x[0] * x[0] + x[1] * x[1] + x[2] * x[2] + x[3] * x[3];
#pragma unroll
            for (int off = 32; off; off >>= 1) {
                s1 += __shfl_xor(s1, off);
                s2 += __shfl_xor(s2, off);
            }
            const float mean = s1 * (1.f / kD);
            const float var = s2 * (1.f / kD) - mean * mean;
            const float rstd = rsqrtf(var + 1e-5f);
            f32x4 g = *(const f32x4*)(lng + c4);
            f32x4 bb = *(const f32x4*)(lnb + c4);
            f32x4 y;
#pragma unroll
            for (int j = 0; j < 4; ++j) y[j] = (x[j] - mean) * rstd * g[j] + bb[j];
            if (MODE == 1) {
                *(f32x4*)(Y + (size_t)row * kD + c4) = y;
            } else {
                const int bnk = row >> 9, s = row & (kS - 1);
                const int nk = bnk & (kNK - 1), b = bnk >> 4;
                *(f32x4*)(Y + (((size_t)(b * kS + s) * kNK + nk) * kD) + c4) = y;
            }
        }
    }
}

// one-row-per-block projection (kept only for tiny Q4: 16 rows)
__global__ __launch_bounds__(256) void proj_kernel(const float* __restrict__ X,
                                                   const float* __restrict__ W,
                                                   const float* __restrict__ bias,
                                                   float* __restrict__ Y, int scatter) {
    const int row = blockIdx.x;
    const int c = threadIdx.x;
    __shared__ float xs[kD];
    xs[c] = X[(size_t)row * kD + c];
    __syncthreads();
    float acc = bias[c];
    const float* wr = W + (size_t)c * kD;
#pragma unroll 4
    for (int k0 = 0; k0 < kD; k0 += 4) {
        f32x4 wv = *(const f32x4*)(wr + k0);
#pragma unroll
        for (int j = 0; j < 4; ++j) acc = fmaf(xs[k0 + j], wv[j], acc);
    }
    if (scatter) {
        const int b = row >> 9, s = row & (kS - 1);
        const int h = c >> 5, dk = c & 31;
        Y[((size_t)(b * kH + h) * kS + s) * kDK + dk] = acc;
    } else {
        Y[(size_t)row * kD + c] = acc;
    }
}

// Block-1 attention v3: 32 q rows/block, 4 waves, MFMA QK^T (split-bf16) + reg softmax + MFMA PV.
// LDS: Sl [32][8*67] f32 | Vt [32][520] bf16 | Pl [32][520] bf16  = 135168 B
__global__ __launch_bounds__(256) void attn1_kernel(const float* __restrict__ Q1,
                                                    const float* __restrict__ V1,
                                                    const float* __restrict__ gam,
                                                    float* __restrict__ q_scores,
                                                    float* __restrict__ A1) {
    extern __shared__ char smem[];
    float* Sl = (float*)smem;                               // 32*536 f32 = 68608 B
    u16* Vt = (u16*)(smem + 32 * 536 * 4);                  // 32*520 bf16 = 33280 B
    u16* Pl = (u16*)(smem + 32 * 536 * 4 + 32 * kPS * 2);   // 32*520 bf16 = 33280 B

    const int bh = blockIdx.x;
    const int q0 = blockIdx.y * 32;
    const int h = bh & (kH - 1);
    const int tid = threadIdx.x;
    const int lane = tid & 63;
    const int w = tid >> 6;
    const float* Kb = Q1 + (size_t)bh * kS * kDK;   // K == Q (shared projection)
    const float* Vb = V1 + (size_t)bh * kS * kDK;

    // Stage V^T (bf16) for PV
#pragma unroll
    for (int it = 0; it < 16; ++it) {
        const int idx = it * 1024 + tid * 4;
        const int k = idx >> 5, d = idx & 31;
        f32x4 v = *(const f32x4*)(Vb + idx);
        Vt[(d + 0) * kPS + k] = f2bf(v[0]);
        Vt[(d + 1) * kPS + k] = f2bf(v[1]);
        Vt[(d + 2) * kPS + k] = f2bf(v[2]);
        Vt[(d + 3) * kPS + k] = f2bf(v[3]);
    }

    // QK^T: split-bf16 3-term MFMA, fragments straight from global (K already B^T-shaped)
    {
        const int qt = w & 1, khalf = w >> 1;
        const int qrow = q0 + qt * 16 + (lane & 15);
        const int dof = (lane >> 4) * 8;
        f32x4 qa = *(const f32x4*)(Kb + (size_t)qrow * kDK + dof);
        f32x4 qb = *(const f32x4*)(Kb + (size_t)qrow * kDK + dof + 4);
        s16x8 aq_h, aq_l;
#pragma unroll
        for (int j = 0; j < 4; ++j) {
            float f = qa[j];
            u16 hi = f2bf(f);
            aq_h[j] = (short)hi;
            aq_l[j] = (short)f2bf(f - bf2f(hi));
            f = qb[j];
            hi = f2bf(f);
            aq_h[4 + j] = (short)hi;
            aq_l[4 + j] = (short)f2bf(f - bf2f(hi));
        }
        for (int kt = khalf * 16; kt < khalf * 16 + 16; ++kt) {
            const int krow = kt * 16 + (lane & 15);
            f32x4 ka = *(const f32x4*)(Kb + (size_t)krow * kDK + dof);
            f32x4 kb2 = *(const f32x4*)(Kb + (size_t)krow * kDK + dof + 4);
            s16x8 bk_h, bk_l;
#pragma unroll
            for (int j = 0; j < 4; ++j) {
                float f = ka[j];
                u16 hi = f2bf(f);
                bk_h[j] = (short)hi;
                bk_l[j] = (short)f2bf(f - bf2f(hi));
                f = kb2[j];
                hi = f2bf(f);
                bk_h[4 + j] = (short)hi;
                bk_l[4 + j] = (short)f2bf(f - bf2f(hi));
            }
            f32x4 acc = {0.f, 0.f, 0.f, 0.f};
            acc = __builtin_amdgcn_mfma_f32_16x16x32_bf16(aq_h, bk_h, acc, 0, 0, 0);
            acc = __builtin_amdgcn_mfma_f32_16x16x32_bf16(aq_l, bk_h, acc, 0, 0, 0);
            acc = __builtin_amdgcn_mfma_f32_16x16x32_bf16(aq_h, bk_l, acc, 0, 0, 0);
            const int colk = kt * 16 + (lane & 15);
            const int seg = colk >> 6, ii = colk & 63;
#pragma unroll
            for (int j = 0; j < 4; ++j) {
                const int row = qt * 16 + (lane >> 4) * 4 + j;
                Sl[row * 536 + seg * 67 + ii] = acc[j] * kScale;
            }
        }
    }
    __syncthreads();

    // Softmax + cumsum + gamma + second softmax: 8 threads per row, 64 elems in regs each
    const float gh = -fabsf(gam[h]);
    {
        const int r = tid >> 3, seg = tid & 7;
        const int q = q0 + r, L = q + 1, ks = seg * 64;
        const float* srow = Sl + r * 536 + seg * 67;
        float sv[64];
#pragma unroll
        for (int i = 0; i < 64; ++i) sv[i] = srow[i];
        const int nv = min(max(L - ks, 0), 64);
        float m = -3e38f;
#pragma unroll
        for (int i = 0; i < 64; ++i)
            if (i < nv) m = fmaxf(m, sv[i]);
#pragma unroll
        for (int off = 1; off < 8; off <<= 1) m = fmaxf(m, __shfl_xor(m, off));
        float segsum = 0.f;
#pragma unroll
        for (int i = 0; i < 64; ++i)
            if (i < nv) segsum += __expf(sv[i] - m);
        float tot = segsum;
#pragma unroll
        for (int off = 1; off < 8; off <<= 1) tot += __shfl_xor(tot, off);
        float inc = segsum;
#pragma unroll
        for (int off = 1; off < 8; off <<= 1) {
            const float tmp = __shfl_up(inc, off);
            if ((tid & 7) >= off) inc += tmp;
        }
        float run = inc - segsum;  // exclusive prefix across segments
        const float inv_tot = 1.f / tot;
        float m2 = -3e38f;
#pragma unroll
        for (int i = 0; i < 64; ++i) {
            if (i < nv) {
                const float E = __expf(sv[i] - m);
                run += E;
                const float rem = 1.f - run * inv_tot;
                const float pos = (float)(q - (ks + i));
                const float val = fmaxf(rem * pos, 0.f);
                const float te = fmaxf(__expf(gh * sqrtf(val)), 1e-5f);
                const float s2 = sv[i] * te;
                sv[i] = s2;
                m2 = fmaxf(m2, s2);
            }
        }
#pragma unroll
        for (int off = 1; off < 8; off <<= 1) m2 = fmaxf(m2, __shfl_xor(m2, off));
        float sum2 = 0.f;
#pragma unroll
        for (int i = 0; i < 64; ++i) {
            const float p = (i < nv) ? __expf(sv[i] - m2) : 0.f;
            sv[i] = p;
            sum2 += p;
        }
#pragma unroll
        for (int off = 1; off < 8; off <<= 1) sum2 += __shfl_xor(sum2, off);
        const float inv2 = 1.f / sum2;
        float* qrow = q_scores + ((size_t)bh * kS + q) * kS + ks;
        u16* prow = Pl + r * kPS + ks;
#pragma unroll
        for (int i = 0; i < 64; i += 4) {
            f32x4 o;
            u16x4 pb;
#pragma unroll
            for (int j = 0; j < 4; ++j) {
                const float p = sv[i + j] * inv2;
                o[j] = p;
                pb[j] = f2bf(p);
            }
            *(f32x4*)(qrow + i) = o;
            *(u16x4*)(prow + i) = pb;
        }
    }
    __syncthreads();

    // PV: O[32q][32d] = P[32x512] * V[512x32], one 16x16 tile per wave
    {
        const int qt = w & 1, dt = w >> 1;
        const u16* Arow = Pl + (size_t)(qt * 16 + (lane & 15)) * kPS + (lane >> 4) * 8;
        const u16* Brow = Vt + (size_t)(dt * 16 + (lane & 15)) * kPS + (lane >> 4) * 8;
        f32x4 acc = {0.f, 0.f, 0.f, 0.f};
#pragma unroll
        for (int kc = 0; kc < kS; kc += 32) {
            s16x8 a = *(const s16x8*)(Arow + kc);
            s16x8 b = *(const s16x8*)(Brow + kc);
            acc = __builtin_amdgcn_mfma_f32_16x16x32_bf16(a, b, acc, 0, 0, 0);
        }
        const int d = dt * 16 + (lane & 15);
#pragma unroll
        for (int j = 0; j < 4; ++j) {
            const int row = qt * 16 + (lane >> 4) * 4 + j;
            A1[((size_t)bh * kS + (q0 + row)) * kDK + d] = acc[j];
        }
    }
}

// Block-4 prep: per panel (b,nk,h): raw scores (length S), stabilized exp, prefix sums.
__global__ __launch_bounds__(64) void attn4_prep(const float* __restrict__ Q4,
                                                 const float* __restrict__ K4,
                                                 float* __restrict__ rawP,
                                                 float* __restrict__ CpreP) {
    const int panel = blockIdx.x;        // (b*NK + nk)*H + h
    const int h = panel & (kH - 1);
    const int bnk = panel >> 3;
    const int nk = bnk & (kNK - 1);
    const int b = bnk >> 4;
    const int lane = threadIdx.x;
    const float* Kp = K4 + (size_t)(b * kH + h) * kS * kDK;
    float qv[kDK];
    const float* Qr = Q4 + (size_t)nk * kD + h * kDK;
#pragma unroll
    for (int d = 0; d < kDK; ++d) qv[d] = Qr[d];

    const int k0 = lane * 8;
    float raw[8];
    float m = -3e38f;
#pragma unroll
    for (int j = 0; j < 8; ++j) {
        const float* kr = Kp + (size_t)(k0 + j) * kDK;
        float s = 0.f;
#pragma unroll
        for (int d = 0; d < kDK; ++d) s = fmaf(qv[d], kr[d], s);
        raw[j] = s * kScale;
        m = fmaxf(m, raw[j]);
    }
    m = wave_max64(m);
    float E[8];
    float s = 0.f;
#pragma unroll
    for (int j = 0; j < 8; ++j) { E[j] = __expf(raw[j] - m); s += E[j]; }
    float inc = s;
#pragma unroll
    for (int off = 1; off < 64; off <<= 1) {
        float t = __shfl_up(inc, off);
        if (lane >= off) inc += t;
    }
    float run = inc - s;   // exclusive prefix of lane sums
    float cp[8];
#pragma unroll
    for (int j = 0; j < 8; ++j) { run += E[j]; cp[j] = run; }

    float* rrow = rawP + (size_t)panel * kS + k0;
    float* crow = CpreP + (size_t)panel * kS + k0;
    *(f32x4*)(rrow) = *(f32x4*)(raw);
    *(f32x4*)(rrow + 4) = *(f32x4*)(raw + 4);
    *(f32x4*)(crow) = *(f32x4*)(cp);
    *(f32x4*)(crow + 4) = *(f32x4*)(cp + 4);
}

// Block-4 main v2: 32 q-rows per block, 4 waves.
__global__ __launch_bounds__(256) void attn4_main(const float* __restrict__ rawP,
                                                  const float* __restrict__ CpreP,
                                                  const float* __restrict__ V4,
                                                  const float* __restrict__ gam,
                                                  float* __restrict__ k_scores,
                                                  float* __restrict__ A4) {
    extern __shared__ char smem[];
    u16* Vt = (u16*)smem;                        // [32][kPS] bf16 (V transposed)
    u16* Pl = (u16*)(smem + 32 * kPS * 2);       // [32][kPS] bf16 (P rows)
    float* raws_l = (float*)(smem + 2 * 32 * kPS * 2);  // [512]
    float* cps_l = raws_l + kS;                  // [512]

    const int panel = blockIdx.x;        // (b*NK + nk)*H + h
    const int q0 = blockIdx.y * 32;
    const int h = panel & (kH - 1);
    const int bnk = panel >> 3;
    const int nk = bnk & (kNK - 1);
    const int b = bnk >> 4;
    const int tid = threadIdx.x;
    const int lane = tid & 63;
    const int w = tid >> 6;

    const float* Vp = V4 + (size_t)(b * kH + h) * kS * kDK;
    for (int idx = tid * 4; idx < kS * kDK; idx += 1024) {
        const int k = idx >> 5, d = idx & 31;
        f32x4 v = *(const f32x4*)(Vp + idx);
        Vt[(d + 0) * kPS + k] = f2bf(v[0]);
        Vt[(d + 1) * kPS + k] = f2bf(v[1]);
        Vt[(d + 2) * kPS + k] = f2bf(v[2]);
        Vt[(d + 3) * kPS + k] = f2bf(v[3]);
    }
    for (int i = tid; i < kS; i += 256) {
        raws_l[i] = rawP[(size_t)panel * kS + i];
        cps_l[i] = CpreP[(size_t)panel * kS + i];
    }
    __syncthreads();

    const float gh = -fabsf(gam[h]);
    const int rbase = w * 8;

    // Phase 1: online softmax stats; lane -> (row = rbase + (lane&7), k-subgroup = lane>>3)
    const int lrow = rbase + (lane & 7);
    const int sub = lane >> 3;
    const int Lq = q0 + lrow;            // strict mask: k < Lq
    const float invCL = 1.f / cps_l[(Lq > 0 ? Lq : 1) - 1];
    float m2 = -3e38f, sum2 = 0.f;
    for (int ks = 0; ks < 64; ++ks) {
        const int k = ks * 8 + sub;
        const float rawk = raws_l[k];
        const float cpk = cps_l[k];
        const bool ok = (k < Lq);
        const float rem = 1.f - cpk * invCL;
        const float val = fmaxf(rem * (float)(Lq - k), 0.f);
        const float te = fmaxf(__expf(gh * sqrtf(val)), 1e-5f);
        const float s2 = rawk * te;
        const float mn = ok ? fmaxf(m2, s2) : m2;
        const float c = ok ? __expf(s2 - mn) : 0.f;
        sum2 = sum2 * __expf(m2 - mn) + c;
        m2 = mn;
    }
#pragma unroll
    for (int off = 8; off < 64; off <<= 1) {
        const float mo = __shfl_xor(m2, off);
        const float so = __shfl_xor(sum2, off);
        const float mn = fmaxf(m2, mo);
        sum2 = sum2 * __expf(m2 - mn) + so * __expf(mo - mn);
        m2 = mn;
    }
    const float scl = fminf(sum2, 5.f) / sum2;   // maxout folded

    // Phase 2: k-on-lanes, rows serial; write k_scores (f32, coalesced) + Pl (bf16)
    const int k0 = lane * 8;
    float rw[8], cp[8];
    *(f32x4*)(rw) = *(const f32x4*)(raws_l + k0);
    *(f32x4*)(rw + 4) = *(const f32x4*)(raws_l + k0 + 4);
    *(f32x4*)(cp) = *(const f32x4*)(cps_l + k0);
    *(f32x4*)(cp + 4) = *(const f32x4*)(cps_l + k0 + 4);

    for (int r = 0; r < 8; ++r) {
        const int row = rbase + r;
        const int Lr = q0 + row;
        const float m2r = __shfl(m2, r);
        const float sclr = __shfl(scl, r);
        const float invr = __shfl(invCL, r);
        float pf[8];
        u16x8 pb;
#pragma unroll
        for (int j = 0; j < 8; ++j) {
            const int k = k0 + j;
            const float rem = 1.f - cp[j] * invr;
            const float val = fmaxf(rem * (float)(Lr - k), 0.f);
            const float te = fmaxf(__expf(gh * sqrtf(val)), 1e-5f);
            const float s2 = rw[j] * te;
            const float p = (k < Lr) ? __expf(s2 - m2r) * sclr : 0.f;
            pf[j] = p;
            pb[j] = f2bf(p);
        }
        float* krow = k_scores + ((size_t)((b * kH + h) * kS + Lr) * kNK + nk) * kS;
        *(f32x4*)(krow + k0) = *(f32x4*)(pf);
        *(f32x4*)(krow + k0 + 4) = *(f32x4*)(pf + 4);
        *(u16x8*)(Pl + (size_t)row * kPS + k0) = pb;
    }
    __syncthreads();

    // Phase 3: MFMA PV
    const int rowblk = (w & 1) * 16;
    const int dblk = (w >> 1) * 16;
    const u16* Arow = Pl + (size_t)(rowblk + (lane & 15)) * kPS + (lane >> 4) * 8;
    const u16* Brow = Vt + (size_t)(dblk + (lane & 15)) * kPS + (lane >> 4) * 8;
    f32x4 acc = {0.f, 0.f, 0.f, 0.f};
#pragma unroll
    for (int kc = 0; kc < kS; kc += 32) {
        s16x8 a = *(const s16x8*)(Arow + kc);
        s16x8 bfr = *(const s16x8*)(Brow + kc);
        acc = __builtin_amdgcn_mfma_f32_16x16x32_bf16(a, bfr, acc, 0, 0, 0);
    }
    const int d = dblk + (lane & 15);
#pragma unroll
    for (int j = 0; j < 4; ++j) {
        const int row = rowblk + (lane >> 4) * 4 + j;
        A4[((size_t)panel * kS + (q0 + row)) * kDK + d] = acc[j];
    }
}

extern "C" void kernel_launch(void* const* d_in, const int* in_sizes, int n_in,
                              void* d_out, int out_size, void* d_ws, size_t ws_size,
                              hipStream_t stream) {
    (void)in_sizes; (void)n_in; (void)out_size; (void)ws_size;

    const float* q_emb = (const float*)d_in[0];
    const float* s_emb = (const float*)d_in[1];
    // d_in[2]=s_emb_extr, d_in[3]=lens, d_in[4]=at : unused by reference
    const float* Wq1 = (const float*)d_in[5];  const float* bq1 = (const float*)d_in[6];
    const float* Wv1 = (const float*)d_in[7];  const float* bv1 = (const float*)d_in[8];
    const float* Wo1 = (const float*)d_in[9];  const float* bo1 = (const float*)d_in[10];
    const float* gam1 = (const float*)d_in[11];
    const float* ln1g = (const float*)d_in[12]; const float* ln1b = (const float*)d_in[13];
    const float* Wq4 = (const float*)d_in[14]; const float* bq4 = (const float*)d_in[15];
    const float* Wk4 = (const float*)d_in[16]; const float* bk4 = (const float*)d_in[17];
    const float* Wv4 = (const float*)d_in[18]; const float* bv4 = (const float*)d_in[19];
    const float* Wo4 = (const float*)d_in[20]; const float* bo4 = (const float*)d_in[21];
    const float* gam4 = (const float*)d_in[22];
    const float* ln4g = (const float*)d_in[23]; const float* ln4b = (const float*)d_in[24];
    const float* know = (const float*)d_in[25];

    float* ws = (float*)d_ws;
    const size_t NBHSD = (size_t)kB * kH * kS * kDK;       // 262144
    float* Q1 = ws;
    float* V1 = Q1 + NBHSD;                                 // freed after attn1 -> rawP/CpreP
    float* A1 = V1 + NBHSD;
    float* P  = A1 + NBHSD;
    float* K4 = P  + (size_t)kB * kS * kD;
    float* V4 = K4 + NBHSD;
    float* Q4 = V4 + NBHSD;                                 // NK*D = 4096
    float* A4 = Q4 + (size_t)kNK * kD;                      // B*NK*H*S*DK = 4194304
    float* WT = A4 + (size_t)kB * kNK * kH * kS * kDK;      // 6 * 65536 floats

    float* rawP = V1;                                       // 131072 floats
    float* CpreP = V1 + (size_t)kB * kNK * kH * kS;         // 131072 floats

    float* WTq1 = WT + 0 * (size_t)kD * kD;
    float* WTv1 = WT + 1 * (size_t)kD * kD;
    float* WTo1 = WT + 2 * (size_t)kD * kD;
    float* WTk4 = WT + 3 * (size_t)kD * kD;
    float* WTv4 = WT + 4 * (size_t)kD * kD;
    float* WTo4 = WT + 5 * (size_t)kD * kD;

    float* zout = (float*)d_out;                            // (B,S,NK*D)
    float* q_scores = zout + (size_t)kB * kS * kNK * kD;    // (B,H,S,S)
    float* k_scores = q_scores + (size_t)kB * kH * kS * kS; // (B,H,S,NK,S)

    // Weight transposes (once per launch; cheap)
    {
        dim3 g(kD, 6);
        wt_kernel<<<g, 256, 0, stream>>>(Wq1, Wv1, Wo1, Wk4, Wv4, Wo4, WT);
    }

    // Block 1
    gemm256<2, 0><<<kB * kS / 8, 256, 0, stream>>>(q_emb, WTq1, bq1, nullptr, nullptr, nullptr, Q1);
    gemm256<2, 0><<<kB * kS / 8, 256, 0, stream>>>(s_emb, WTv1, bv1, nullptr, nullptr, nullptr, V1);
    {
        dim3 g1(kB * kH, kS / 32);
        const int lds1 = 32 * 536 * 4 + 2 * 32 * kPS * 2;   // 135168
        attn1_kernel<<<g1, 256, lds1, stream>>>(Q1, V1, gam1, q_scores, A1);
    }
    gemm256<2, 1><<<kB * kS / 8, 256, 0, stream>>>(A1, WTo1, bo1, q_emb, ln1g, ln1b, P);

    // Block 4 projections (V1 dead from here; reused as rawP/CpreP)
    gemm256<2, 0><<<kB * kS / 8, 256, 0, stream>>>(q_emb, WTk4, bk4, nullptr, nullptr, nullptr, K4);
    gemm256<2, 0><<<kB * kS / 8, 256, 0, stream>>>(P, WTv4, bv4, nullptr, nullptr, nullptr, V4);
    proj_kernel<<<kNK, 256, 0, stream>>>(know, Wq4, bq4, Q4, 0);

    // Block 4 attention
    attn4_prep<<<kB * kNK * kH, 64, 0, stream>>>(Q4, K4, rawP, CpreP);
    {
        dim3 g5(kB * kNK * kH, kS / 32);
        const int lds_bytes = 2 * 32 * kPS * 2 + 2 * kS * 4;  // 70656
        attn4_main<<<g5, 256, lds_bytes, stream>>>(rawP, CpreP, V4, gam4, k_scores, A4);
    }

    // Block 4 epilogue (tiled GEMM + LN + scatter)
    gemm256<8, 2><<<kB * kNK * kS / 32, 256, 0, stream>>>(A4, WTo4, bo4, know, ln4g, ln4b, zout);
}

// Round 7
// 294.624 us; speedup vs baseline: 7.7168x; 1.1403x over previous
//
#include <hip/hip_runtime.h>

// DTransformer forward (f32 in/out, f32 internal)
// B=2 S=512 D=256 H=8 DK=32 NK=16

namespace {
constexpr int kB = 2, kS = 512, kD = 256, kH = 8, kDK = 32, kNK = 16;
constexpr float kScale = 0.17677669529663687f;  // 1/sqrt(32)
constexpr int kPS = 520;                        // padded LDS row stride (bf16 elems)
}

typedef unsigned short u16;
typedef u16 u16x4 __attribute__((ext_vector_type(4)));
typedef u16 u16x8 __attribute__((ext_vector_type(8)));
typedef short s16x8 __attribute__((ext_vector_type(8)));
typedef float f32x4 __attribute__((ext_vector_type(4)));

__device__ __forceinline__ float bf2f(u16 u) { return __uint_as_float(((unsigned)u) << 16); }
__device__ __forceinline__ u16 f2bf(float f) {
    unsigned u = __float_as_uint(f);
    return (u16)((u + 0x7fffu + ((u >> 16) & 1u)) >> 16);
}

__device__ __forceinline__ float wave_max64(float v) {
#pragma unroll
    for (int off = 32; off; off >>= 1) v = fmaxf(v, __shfl_xor(v, off));
    return v;
}
__device__ __forceinline__ float wave_sum64(float v) {
#pragma unroll
    for (int off = 32; off; off >>= 1) v += __shfl_xor(v, off);
    return v;
}

// Transpose 6 weight matrices [c][k] -> [k][c] (256x256 each)
__global__ __launch_bounds__(256) void wt_kernel(const float* __restrict__ W0,
                                                 const float* __restrict__ W1,
                                                 const float* __restrict__ W2,
                                                 const float* __restrict__ W3,
                                                 const float* __restrict__ W4,
                                                 const float* __restrict__ W5,
                                                 float* __restrict__ WT) {
    const float* srcs[6] = {W0, W1, W2, W3, W4, W5};
    const float* W = srcs[blockIdx.y];
    float* T = WT + (size_t)blockIdx.y * kD * kD;
    const int k = blockIdx.x, c = threadIdx.x;
    T[(size_t)k * kD + c] = W[(size_t)c * kD + k];
}

// Unified tiled GEMM: Y[row,c] = sum_k X[row,k]*W[c,k] + bias[c], W given transposed.
// MODE 0: X plain [row][256], Y scattered to [(row>>9)*8+h][s][dk]
// MODE 1: X gathered from A-layout, +extra[row][c] residual, LN, Y plain [row][256]
// MODE 2: X gathered from A-layout, +extra[nk][c], LN, Y scattered to [(b,s,nk)][c]
template <int RPW, int MODE>
__global__ __launch_bounds__(256) void gemm256(const float* __restrict__ X,
                                               const float* __restrict__ WT,
                                               const float* __restrict__ bias,
                                               const float* __restrict__ extra,
                                               const float* __restrict__ lng,
                                               const float* __restrict__ lnb,
                                               float* __restrict__ Y) {
    constexpr int TM = RPW * 4;
    __shared__ float xs[TM][kD];
    const int t = threadIdx.x;
    const int r0 = blockIdx.x * TM;

    if (MODE == 0) {
#pragma unroll
        for (int it = 0; it < RPW; ++it) {
            const int idx = it * 1024 + t * 4;
            const int r = idx >> 8, c = idx & 255;
            *(f32x4*)&xs[r][c] = *(const f32x4*)(X + (size_t)(r0 + r) * kD + c);
        }
    } else {
#pragma unroll
        for (int it = 0; it < RPW; ++it) {
            const int chunk = it * 32 + (t >> 3);   // 0..TM*8-1
            const int r = chunk >> 3, h = chunk & 7;
            const int row = r0 + r;
            const float* src = X + (((size_t)(row >> 9) * kH + h) * kS + (row & (kS - 1))) * kDK + (t & 7) * 4;
            *(f32x4*)&xs[r][h * kDK + (t & 7) * 4] = *(const f32x4*)src;
        }
    }
    __syncthreads();

    const int wv = t >> 6;
    const int c4 = (t & 63) * 4;
    float acc[RPW][4];
    {
        f32x4 bv = *(const f32x4*)(bias + c4);
#pragma unroll
        for (int r = 0; r < RPW; ++r)
#pragma unroll
            for (int j = 0; j < 4; ++j) acc[r][j] = bv[j];
    }
    for (int k0 = 0; k0 < kD; k0 += 4) {
        f32x4 w0 = *(const f32x4*)(WT + (size_t)(k0 + 0) * kD + c4);
        f32x4 w1 = *(const f32x4*)(WT + (size_t)(k0 + 1) * kD + c4);
        f32x4 w2 = *(const f32x4*)(WT + (size_t)(k0 + 2) * kD + c4);
        f32x4 w3 = *(const f32x4*)(WT + (size_t)(k0 + 3) * kD + c4);
#pragma unroll
        for (int r = 0; r < RPW; ++r) {
            f32x4 xv = *(const f32x4*)&xs[wv * RPW + r][k0];
#pragma unroll
            for (int cc = 0; cc < 4; ++cc) {
                acc[r][cc] = fmaf(xv[0], w0[cc], acc[r][cc]);
                acc[r][cc] = fmaf(xv[1], w1[cc], acc[r][cc]);
                acc[r][cc] = fmaf(xv[2], w2[cc], acc[r][cc]);
                acc[r][cc] = fmaf(xv[3], w3[cc], acc[r][cc]);
            }
        }
    }

#pragma unroll
    for (int r = 0; r < RPW; ++r) {
        const int row = r0 + wv * RPW + r;
        if (MODE == 0) {
            const int h = c4 >> 5, dk = c4 & 31;
            *(f32x4*)(Y + (((size_t)(row >> 9) * kH + h) * kS + (row & (kS - 1))) * kDK + dk) =
                *(f32x4*)acc[r];
        } else {
            f32x4 x;
            if (MODE == 1) {
                f32x4 e = *(const f32x4*)(extra + (size_t)row * kD + c4);
#pragma unroll
                for (int j = 0; j < 4; ++j) x[j] = acc[r][j] + e[j];
            } else {
                const int nk = (row >> 9) & (kNK - 1);
                f32x4 e = *(const f32x4*)(extra + (size_t)nk * kD + c4);
#pragma unroll
                for (int j = 0; j < 4; ++j) x[j] = acc[r][j] + e[j];
            }
            float s1 = x[0] + x[1] + x[2] + x[3];
            float s2 = x[0] * x[0] + x[1] * x[1] + x[2] * x[2] + x[3] * x[3];
#pragma unroll
            for (int off = 32; off; off >>= 1) {
                s1 += __shfl_xor(s1, off);
                s2 += __shfl_xor(s2, off);
            }
            const float mean = s1 * (1.f / kD);
            const float var = s2 * (1.f / kD) - mean * mean;
            const float rstd = rsqrtf(var + 1e-5f);
            f32x4 g = *(const f32x4*)(lng + c4);
            f32x4 bb = *(const f32x4*)(lnb + c4);
            f32x4 y;
#pragma unroll
            for (int j = 0; j < 4; ++j) y[j] = (x[j] - mean) * rstd * g[j] + bb[j];
            if (MODE == 1) {
                *(f32x4*)(Y + (size_t)row * kD + c4) = y;
            } else {
                const int bnk = row >> 9, s = row & (kS - 1);
                const int nk = bnk & (kNK - 1), b = bnk >> 4;
                *(f32x4*)(Y + (((size_t)(b * kS + s) * kNK + nk) * kD) + c4) = y;
            }
        }
    }
}

// one-row-per-block projection (kept only for tiny Q4: 16 rows)
__global__ __launch_bounds__(256) void proj_kernel(const float* __restrict__ X,
                                                   const float* __restrict__ W,
                                                   const float* __restrict__ bias,
                                                   float* __restrict__ Y, int scatter) {
    const int row = blockIdx.x;
    const int c = threadIdx.x;
    __shared__ float xs[kD];
    xs[c] = X[(size_t)row * kD + c];
    __syncthreads();
    float acc = bias[c];
    const float* wr = W + (size_t)c * kD;
#pragma unroll 4
    for (int k0 = 0; k0 < kD; k0 += 4) {
        f32x4 wv = *(const f32x4*)(wr + k0);
#pragma unroll
        for (int j = 0; j < 4; ++j) acc = fmaf(xs[k0 + j], wv[j], acc);
    }
    if (scatter) {
        const int b = row >> 9, s = row & (kS - 1);
        const int h = c >> 5, dk = c & 31;
        Y[((size_t)(b * kH + h) * kS + s) * kDK + dk] = acc;
    } else {
        Y[(size_t)row * kD + c] = acc;
    }
}

// Block-1 attention v3: 32 q rows/block, 4 waves, MFMA QK^T (split-bf16) + reg softmax + MFMA PV.
// LDS: Sl [32][8*67] f32 | Vt [32][520] bf16 | Pl [32][520] bf16  = 135168 B
__global__ __launch_bounds__(256) void attn1_kernel(const float* __restrict__ Q1,
                                                    const float* __restrict__ V1,
                                                    const float* __restrict__ gam,
                                                    float* __restrict__ q_scores,
                                                    float* __restrict__ A1) {
    extern __shared__ char smem[];
    float* Sl = (float*)smem;                               // 32*536 f32 = 68608 B
    u16* Vt = (u16*)(smem + 32 * 536 * 4);                  // 32*520 bf16 = 33280 B
    u16* Pl = (u16*)(smem + 32 * 536 * 4 + 32 * kPS * 2);   // 32*520 bf16 = 33280 B

    const int bh = blockIdx.x;
    const int q0 = blockIdx.y * 32;
    const int h = bh & (kH - 1);
    const int tid = threadIdx.x;
    const int lane = tid & 63;
    const int w = tid >> 6;
    const float* Kb = Q1 + (size_t)bh * kS * kDK;   // K == Q (shared projection)
    const float* Vb = V1 + (size_t)bh * kS * kDK;

    // Stage V^T (bf16) for PV
#pragma unroll
    for (int it = 0; it < 16; ++it) {
        const int idx = it * 1024 + tid * 4;
        const int k = idx >> 5, d = idx & 31;
        f32x4 v = *(const f32x4*)(Vb + idx);
        Vt[(d + 0) * kPS + k] = f2bf(v[0]);
        Vt[(d + 1) * kPS + k] = f2bf(v[1]);
        Vt[(d + 2) * kPS + k] = f2bf(v[2]);
        Vt[(d + 3) * kPS + k] = f2bf(v[3]);
    }

    // QK^T: split-bf16 3-term MFMA, fragments straight from global (K already B^T-shaped)
    {
        const int qt = w & 1, khalf = w >> 1;
        const int qrow = q0 + qt * 16 + (lane & 15);
        const int dof = (lane >> 4) * 8;
        f32x4 qa = *(const f32x4*)(Kb + (size_t)qrow * kDK + dof);
        f32x4 qb = *(const f32x4*)(Kb + (size_t)qrow * kDK + dof + 4);
        s16x8 aq_h, aq_l;
#pragma unroll
        for (int j = 0; j < 4; ++j) {
            float f = qa[j];
            u16 hi = f2bf(f);
            aq_h[j] = (short)hi;
            aq_l[j] = (short)f2bf(f - bf2f(hi));
            f = qb[j];
            hi = f2bf(f);
            aq_h[4 + j] = (short)hi;
            aq_l[4 + j] = (short)f2bf(f - bf2f(hi));
        }
        for (int kt = khalf * 16; kt < khalf * 16 + 16; ++kt) {
            const int krow = kt * 16 + (lane & 15);
            f32x4 ka = *(const f32x4*)(Kb + (size_t)krow * kDK + dof);
            f32x4 kb2 = *(const f32x4*)(Kb + (size_t)krow * kDK + dof + 4);
            s16x8 bk_h, bk_l;
#pragma unroll
            for (int j = 0; j < 4; ++j) {
                float f = ka[j];
                u16 hi = f2bf(f);
                bk_h[j] = (short)hi;
                bk_l[j] = (short)f2bf(f - bf2f(hi));
                f = kb2[j];
                hi = f2bf(f);
                bk_h[4 + j] = (short)hi;
                bk_l[4 + j] = (short)f2bf(f - bf2f(hi));
            }
            f32x4 acc = {0.f, 0.f, 0.f, 0.f};
            acc = __builtin_amdgcn_mfma_f32_16x16x32_bf16(aq_h, bk_h, acc, 0, 0, 0);
            acc = __builtin_amdgcn_mfma_f32_16x16x32_bf16(aq_l, bk_h, acc, 0, 0, 0);
            acc = __builtin_amdgcn_mfma_f32_16x16x32_bf16(aq_h, bk_l, acc, 0, 0, 0);
            const int colk = kt * 16 + (lane & 15);
            const int seg = colk >> 6, ii = colk & 63;
#pragma unroll
            for (int j = 0; j < 4; ++j) {
                const int row = qt * 16 + (lane >> 4) * 4 + j;
                Sl[row * 536 + seg * 67 + ii] = acc[j] * kScale;
            }
        }
    }
    __syncthreads();

    // Softmax + cumsum + gamma + second softmax: 8 threads per row, 64 elems in regs each
    const float gh = -fabsf(gam[h]);
    {
        const int r = tid >> 3, seg = tid & 7;
        const int q = q0 + r, L = q + 1, ks = seg * 64;
        const float* srow = Sl + r * 536 + seg * 67;
        float sv[64];
#pragma unroll
        for (int i = 0; i < 64; ++i) sv[i] = srow[i];
        const int nv = min(max(L - ks, 0), 64);
        float m = -3e38f;
#pragma unroll
        for (int i = 0; i < 64; ++i)
            if (i < nv) m = fmaxf(m, sv[i]);
#pragma unroll
        for (int off = 1; off < 8; off <<= 1) m = fmaxf(m, __shfl_xor(m, off));
        float segsum = 0.f;
#pragma unroll
        for (int i = 0; i < 64; ++i)
            if (i < nv) segsum += __expf(sv[i] - m);
        float tot = segsum;
#pragma unroll
        for (int off = 1; off < 8; off <<= 1) tot += __shfl_xor(tot, off);
        float inc = segsum;
#pragma unroll
        for (int off = 1; off < 8; off <<= 1) {
            const float tmp = __shfl_up(inc, off);
            if ((tid & 7) >= off) inc += tmp;
        }
        float run = inc - segsum;  // exclusive prefix across segments
        const float inv_tot = 1.f / tot;
        float m2 = -3e38f;
#pragma unroll
        for (int i = 0; i < 64; ++i) {
            if (i < nv) {
                const float E = __expf(sv[i] - m);
                run += E;
                const float rem = 1.f - run * inv_tot;
                const float pos = (float)(q - (ks + i));
                const float val = fmaxf(rem * pos, 0.f);
                const float te = fmaxf(__expf(gh * sqrtf(val)), 1e-5f);
                const float s2 = sv[i] * te;
                sv[i] = s2;
                m2 = fmaxf(m2, s2);
            }
        }
#pragma unroll
        for (int off = 1; off < 8; off <<= 1) m2 = fmaxf(m2, __shfl_xor(m2, off));
        float sum2 = 0.f;
#pragma unroll
        for (int i = 0; i < 64; ++i) {
            const float p = (i < nv) ? __expf(sv[i] - m2) : 0.f;
            sv[i] = p;
            sum2 += p;
        }
#pragma unroll
        for (int off = 1; off < 8; off <<= 1) sum2 += __shfl_xor(sum2, off);
        const float inv2 = 1.f / sum2;
        float* qrow = q_scores + ((size_t)bh * kS + q) * kS + ks;
        u16* prow = Pl + r * kPS + ks;
#pragma unroll
        for (int i = 0; i < 64; i += 4) {
            f32x4 o;
            u16x4 pb;
#pragma unroll
            for (int j = 0; j < 4; ++j) {
                const float p = sv[i + j] * inv2;
                o[j] = p;
                pb[j] = f2bf(p);
            }
            *(f32x4*)(qrow + i) = o;
            *(u16x4*)(prow + i) = pb;
        }
    }
    __syncthreads();

    // PV: O[32q][32d] = P[32x512] * V[512x32], one 16x16 tile per wave
    {
        const int qt = w & 1, dt = w >> 1;
        const u16* Arow = Pl + (size_t)(qt * 16 + (lane & 15)) * kPS + (lane >> 4) * 8;
        const u16* Brow = Vt + (size_t)(dt * 16 + (lane & 15)) * kPS + (lane >> 4) * 8;
        f32x4 acc = {0.f, 0.f, 0.f, 0.f};
#pragma unroll
        for (int kc = 0; kc < kS; kc += 32) {
            s16x8 a = *(const s16x8*)(Arow + kc);
            s16x8 b = *(const s16x8*)(Brow + kc);
            acc = __builtin_amdgcn_mfma_f32_16x16x32_bf16(a, b, acc, 0, 0, 0);
        }
        const int d = dt * 16 + (lane & 15);
#pragma unroll
        for (int j = 0; j < 4; ++j) {
            const int row = qt * 16 + (lane >> 4) * 4 + j;
            A1[((size_t)bh * kS + (q0 + row)) * kDK + d] = acc[j];
        }
    }
}

// Block-4 prep: per panel (b,nk,h): raw scores (length S), stabilized exp, prefix sums.
__global__ __launch_bounds__(64) void attn4_prep(const float* __restrict__ Q4,
                                                 const float* __restrict__ K4,
                                                 float* __restrict__ rawP,
                                                 float* __restrict__ CpreP) {
    const int panel = blockIdx.x;        // (b*NK + nk)*H + h
    const int h = panel & (kH - 1);
    const int bnk = panel >> 3;
    const int nk = bnk & (kNK - 1);
    const int b = bnk >> 4;
    const int lane = threadIdx.x;
    const float* Kp = K4 + (size_t)(b * kH + h) * kS * kDK;
    float qv[kDK];
    const float* Qr = Q4 + (size_t)nk * kD + h * kDK;
#pragma unroll
    for (int d = 0; d < kDK; ++d) qv[d] = Qr[d];

    const int k0 = lane * 8;
    float raw[8];
    float m = -3e38f;
#pragma unroll
    for (int j = 0; j < 8; ++j) {
        const float* kr = Kp + (size_t)(k0 + j) * kDK;
        float s = 0.f;
#pragma unroll
        for (int d = 0; d < kDK; ++d) s = fmaf(qv[d], kr[d], s);
        raw[j] = s * kScale;
        m = fmaxf(m, raw[j]);
    }
    m = wave_max64(m);
    float E[8];
    float s = 0.f;
#pragma unroll
    for (int j = 0; j < 8; ++j) { E[j] = __expf(raw[j] - m); s += E[j]; }
    float inc = s;
#pragma unroll
    for (int off = 1; off < 64; off <<= 1) {
        float t = __shfl_up(inc, off);
        if (lane >= off) inc += t;
    }
    float run = inc - s;   // exclusive prefix of lane sums
    float cp[8];
#pragma unroll
    for (int j = 0; j < 8; ++j) { run += E[j]; cp[j] = run; }

    float* rrow = rawP + (size_t)panel * kS + k0;
    float* crow = CpreP + (size_t)panel * kS + k0;
    *(f32x4*)(rrow) = *(f32x4*)(raw);
    *(f32x4*)(rrow + 4) = *(f32x4*)(raw + 4);
    *(f32x4*)(crow) = *(f32x4*)(cp);
    *(f32x4*)(crow + 4) = *(f32x4*)(cp + 4);
}

// Block-4 main v3: 32 q-rows per block, 4 waves; single fused softmax pass
// (k-on-lanes, rows serial, 2 wave-reductions/row) + MFMA PV.
__global__ __launch_bounds__(256) void attn4_main(const float* __restrict__ rawP,
                                                  const float* __restrict__ CpreP,
                                                  const float* __restrict__ V4,
                                                  const float* __restrict__ gam,
                                                  float* __restrict__ k_scores,
                                                  float* __restrict__ A4) {
    extern __shared__ char smem[];
    u16* Vt = (u16*)smem;                        // [32][kPS] bf16 (V transposed)
    u16* Pl = (u16*)(smem + 32 * kPS * 2);       // [32][kPS] bf16 (P rows)
    float* raws_l = (float*)(smem + 2 * 32 * kPS * 2);  // [512]
    float* cps_l = raws_l + kS;                  // [512]

    const int panel = blockIdx.x;        // (b*NK + nk)*H + h
    const int q0 = blockIdx.y * 32;
    const int h = panel & (kH - 1);
    const int bnk = panel >> 3;
    const int nk = bnk & (kNK - 1);
    const int b = bnk >> 4;
    const int tid = threadIdx.x;
    const int lane = tid & 63;
    const int w = tid >> 6;

    const float* Vp = V4 + (size_t)(b * kH + h) * kS * kDK;
    for (int idx = tid * 4; idx < kS * kDK; idx += 1024) {
        const int k = idx >> 5, d = idx & 31;
        f32x4 v = *(const f32x4*)(Vp + idx);
        Vt[(d + 0) * kPS + k] = f2bf(v[0]);
        Vt[(d + 1) * kPS + k] = f2bf(v[1]);
        Vt[(d + 2) * kPS + k] = f2bf(v[2]);
        Vt[(d + 3) * kPS + k] = f2bf(v[3]);
    }
    for (int i = tid; i < kS; i += 256) {
        raws_l[i] = rawP[(size_t)panel * kS + i];
        cps_l[i] = CpreP[(size_t)panel * kS + i];
    }
    __syncthreads();

    const float gh = -fabsf(gam[h]);
    const int rbase = w * 8;
    const int k0 = lane * 8;
    // row-invariant per-lane data
    float rw[8], cp[8];
    *(f32x4*)(rw) = *(const f32x4*)(raws_l + k0);
    *(f32x4*)(rw + 4) = *(const f32x4*)(raws_l + k0 + 4);
    *(f32x4*)(cp) = *(const f32x4*)(cps_l + k0);
    *(f32x4*)(cp + 4) = *(const f32x4*)(cps_l + k0 + 4);

    for (int r = 0; r < 8; ++r) {
        const int row = rbase + r;
        const int Lr = q0 + row;         // strict mask: k < Lr
        float* krow = k_scores + ((size_t)((b * kH + h) * kS + Lr) * kNK + nk) * kS;
        u16* prow = Pl + (size_t)row * kPS + k0;
        if (Lr == 0) {
            f32x4 z = {0.f, 0.f, 0.f, 0.f};
            *(f32x4*)(krow + k0) = z;
            *(f32x4*)(krow + k0 + 4) = z;
            u16x8 zb = {0, 0, 0, 0, 0, 0, 0, 0};
            *(u16x8*)(prow) = zb;
            continue;
        }
        const float invCL = 1.f / cps_l[Lr - 1];
        const float fL = (float)(Lr - k0);
        float s2v[8];
        float mloc = -3e38f;
#pragma unroll
        for (int j = 0; j < 8; ++j) {
            const float rem = 1.f - cp[j] * invCL;
            const float val = fmaxf(rem * (fL - (float)j), 0.f);
            const float te = fmaxf(__expf(gh * sqrtf(val)), 1e-5f);
            const float s2 = rw[j] * te;
            s2v[j] = s2;
            if (k0 + j < Lr) mloc = fmaxf(mloc, s2);
        }
        const float m2 = wave_max64(mloc);
        float p[8];
        float psum = 0.f;
#pragma unroll
        for (int j = 0; j < 8; ++j) {
            p[j] = (k0 + j < Lr) ? __expf(s2v[j] - m2) : 0.f;
            psum += p[j];
        }
        const float sum2 = wave_sum64(psum);
        const float scl = fminf(sum2, 5.f) / sum2;   // maxout folded (max p = 1/sum2)
        u16x8 pb;
#pragma unroll
        for (int j = 0; j < 8; ++j) {
            p[j] *= scl;
            pb[j] = f2bf(p[j]);
        }
        *(f32x4*)(krow + k0) = *(f32x4*)(p);
        *(f32x4*)(krow + k0 + 4) = *(f32x4*)(p + 4);
        *(u16x8*)(prow) = pb;
    }
    __syncthreads();

    // MFMA PV
    const int rowblk = (w & 1) * 16;
    const int dblk = (w >> 1) * 16;
    const u16* Arow = Pl + (size_t)(rowblk + (lane & 15)) * kPS + (lane >> 4) * 8;
    const u16* Brow = Vt + (size_t)(dblk + (lane & 15)) * kPS + (lane >> 4) * 8;
    f32x4 acc = {0.f, 0.f, 0.f, 0.f};
#pragma unroll
    for (int kc = 0; kc < kS; kc += 32) {
        s16x8 a = *(const s16x8*)(Arow + kc);
        s16x8 bfr = *(const s16x8*)(Brow + kc);
        acc = __builtin_amdgcn_mfma_f32_16x16x32_bf16(a, bfr, acc, 0, 0, 0);
    }
    const int d = dblk + (lane & 15);
#pragma unroll
    for (int j = 0; j < 4; ++j) {
        const int row = rowblk + (lane >> 4) * 4 + j;
        A4[((size_t)panel * kS + (q0 + row)) * kDK + d] = acc[j];
    }
}

extern "C" void kernel_launch(void* const* d_in, const int* in_sizes, int n_in,
                              void* d_out, int out_size, void* d_ws, size_t ws_size,
                              hipStream_t stream) {
    (void)in_sizes; (void)n_in; (void)out_size; (void)ws_size;

    const float* q_emb = (const float*)d_in[0];
    const float* s_emb = (const float*)d_in[1];
    // d_in[2]=s_emb_extr, d_in[3]=lens, d_in[4]=at : unused by reference
    const float* Wq1 = (const float*)d_in[5];  const float* bq1 = (const float*)d_in[6];
    const float* Wv1 = (const float*)d_in[7];  const float* bv1 = (const float*)d_in[8];
    const float* Wo1 = (const float*)d_in[9];  const float* bo1 = (const float*)d_in[10];
    const float* gam1 = (const float*)d_in[11];
    const float* ln1g = (const float*)d_in[12]; const float* ln1b = (const float*)d_in[13];
    const float* Wq4 = (const float*)d_in[14]; const float* bq4 = (const float*)d_in[15];
    const float* Wk4 = (const float*)d_in[16]; const float* bk4 = (const float*)d_in[17];
    const float* Wv4 = (const float*)d_in[18]; const float* bv4 = (const float*)d_in[19];
    const float* Wo4 = (const float*)d_in[20]; const float* bo4 = (const float*)d_in[21];
    const float* gam4 = (const float*)d_in[22];
    const float* ln4g = (const float*)d_in[23]; const float* ln4b = (const float*)d_in[24];
    const float* know = (const float*)d_in[25];

    float* ws = (float*)d_ws;
    const size_t NBHSD = (size_t)kB * kH * kS * kDK;       // 262144
    float* Q1 = ws;
    float* V1 = Q1 + NBHSD;                                 // freed after attn1 -> rawP/CpreP
    float* A1 = V1 + NBHSD;
    float* P  = A1 + NBHSD;
    float* K4 = P  + (size_t)kB * kS * kD;
    float* V4 = K4 + NBHSD;
    float* Q4 = V4 + NBHSD;                                 // NK*D = 4096
    float* A4 = Q4 + (size_t)kNK * kD;                      // B*NK*H*S*DK = 4194304
    float* WT = A4 + (size_t)kB * kNK * kH * kS * kDK;      // 6 * 65536 floats

    float* rawP = V1;                                       // 131072 floats
    float* CpreP = V1 + (size_t)kB * kNK * kH * kS;         // 131072 floats

    float* WTq1 = WT + 0 * (size_t)kD * kD;
    float* WTv1 = WT + 1 * (size_t)kD * kD;
    float* WTo1 = WT + 2 * (size_t)kD * kD;
    float* WTk4 = WT + 3 * (size_t)kD * kD;
    float* WTv4 = WT + 4 * (size_t)kD * kD;
    float* WTo4 = WT + 5 * (size_t)kD * kD;

    float* zout = (float*)d_out;                            // (B,S,NK*D)
    float* q_scores = zout + (size_t)kB * kS * kNK * kD;    // (B,H,S,S)
    float* k_scores = q_scores + (size_t)kB * kH * kS * kS; // (B,H,S,NK,S)

    // Weight transposes (once per launch; cheap)
    {
        dim3 g(kD, 6);
        wt_kernel<<<g, 256, 0, stream>>>(Wq1, Wv1, Wo1, Wk4, Wv4, Wo4, WT);
    }

    // Block 1
    gemm256<1, 0><<<kB * kS / 4, 256, 0, stream>>>(q_emb, WTq1, bq1, nullptr, nullptr, nullptr, Q1);
    gemm256<1, 0><<<kB * kS / 4, 256, 0, stream>>>(s_emb, WTv1, bv1, nullptr, nullptr, nullptr, V1);
    {
        dim3 g1(kB * kH, kS / 32);
        const int lds1 = 32 * 536 * 4 + 2 * 32 * kPS * 2;   // 135168
        attn1_kernel<<<g1, 256, lds1, stream>>>(Q1, V1, gam1, q_scores, A1);
    }
    gemm256<1, 1><<<kB * kS / 4, 256, 0, stream>>>(A1, WTo1, bo1, q_emb, ln1g, ln1b, P);

    // Block 4 projections (V1 dead from here; reused as rawP/CpreP)
    gemm256<1, 0><<<kB * kS / 4, 256, 0, stream>>>(q_emb, WTk4, bk4, nullptr, nullptr, nullptr, K4);
    gemm256<1, 0><<<kB * kS / 4, 256, 0, stream>>>(P, WTv4, bv4, nullptr, nullptr, nullptr, V4);
    proj_kernel<<<kNK, 256, 0, stream>>>(know, Wq4, bq4, Q4, 0);

    // Block 4 attention
    attn4_prep<<<kB * kNK * kH, 64, 0, stream>>>(Q4, K4, rawP, CpreP);
    {
        dim3 g5(kB * kNK * kH, kS / 32);
        const int lds_bytes = 2 * 32 * kPS * 2 + 2 * kS * 4;  // 70656
        attn4_main<<<g5, 256, lds_bytes, stream>>>(rawP, CpreP, V4, gam4, k_scores, A4);
    }

    // Block 4 epilogue (tiled GEMM + LN + scatter)
    gemm256<8, 2><<<kB * kNK * kS / 32, 256, 0, stream>>>(A4, WTo4, bo4, know, ln4g, ln4b, zout);
}

// Round 8
// 230.208 us; speedup vs baseline: 9.8760x; 1.2798x over previous
//
#include <hip/hip_runtime.h>

// DTransformer forward (f32 in/out, f32 internal)
// B=2 S=512 D=256 H=8 DK=32 NK=16

namespace {
constexpr int kB = 2, kS = 512, kD = 256, kH = 8, kDK = 32, kNK = 16;
constexpr float kScale = 0.17677669529663687f;  // 1/sqrt(32)
constexpr int kPS = 520;                        // padded LDS row stride (bf16 elems)
}

typedef unsigned short u16;
typedef u16 u16x4 __attribute__((ext_vector_type(4)));
typedef u16 u16x8 __attribute__((ext_vector_type(8)));
typedef short s16x8 __attribute__((ext_vector_type(8)));
typedef float f32x4 __attribute__((ext_vector_type(4)));

__device__ __forceinline__ float bf2f(u16 u) { return __uint_as_float(((unsigned)u) << 16); }
__device__ __forceinline__ u16 f2bf(float f) {
    unsigned u = __float_as_uint(f);
    return (u16)((u + 0x7fffu + ((u >> 16) & 1u)) >> 16);
}

__device__ __forceinline__ float wave_max64(float v) {
#pragma unroll
    for (int off = 32; off; off >>= 1) v = fmaxf(v, __shfl_xor(v, off));
    return v;
}
__device__ __forceinline__ float wave_sum64(float v) {
#pragma unroll
    for (int off = 32; off; off >>= 1) v += __shfl_xor(v, off);
    return v;
}

// Transpose 6 weight matrices [c][k] -> [k][c] (256x256 each)
__global__ __launch_bounds__(256) void wt_kernel(const float* __restrict__ W0,
                                                 const float* __restrict__ W1,
                                                 const float* __restrict__ W2,
                                                 const float* __restrict__ W3,
                                                 const float* __restrict__ W4,
                                                 const float* __restrict__ W5,
                                                 float* __restrict__ WT) {
    const float* srcs[6] = {W0, W1, W2, W3, W4, W5};
    const float* W = srcs[blockIdx.y];
    float* T = WT + (size_t)blockIdx.y * kD * kD;
    const int k = blockIdx.x, c = threadIdx.x;
    T[(size_t)k * kD + c] = W[(size_t)c * kD + k];
}

// V4 [bh][k][dk] f32 -> Vtg [bh][dk][k] bf16 (one-shot transpose+convert)
__global__ __launch_bounds__(256) void vt4_kernel(const float* __restrict__ V4,
                                                  u16* __restrict__ Vtg) {
    __shared__ float tile[128][33];
    const int bh = blockIdx.x, kt = blockIdx.y;   // kt in [0,4)
    const int t = threadIdx.x;
    const float* src = V4 + ((size_t)bh * kS + kt * 128) * kDK;
    for (int i = t * 4; i < 128 * 32; i += 1024) {
        f32x4 v = *(const f32x4*)(src + i);
        const int k = i >> 5, d = i & 31;
        tile[k][d] = v[0]; tile[k][d + 1] = v[1];
        tile[k][d + 2] = v[2]; tile[k][d + 3] = v[3];
    }
    __syncthreads();
    const int d = t >> 3, kc = (t & 7) * 16;
    u16* dst = Vtg + ((size_t)bh * kDK + d) * kS + kt * 128 + kc;
    u16x8 o1, o2;
#pragma unroll
    for (int j = 0; j < 8; ++j) o1[j] = f2bf(tile[kc + j][d]);
#pragma unroll
    for (int j = 0; j < 8; ++j) o2[j] = f2bf(tile[kc + 8 + j][d]);
    *(u16x8*)dst = o1;
    *(u16x8*)(dst + 8) = o2;
}

// Unified tiled GEMM (see MODE docs in earlier rounds)
template <int RPW, int MODE>
__global__ __launch_bounds__(256) void gemm256(const float* __restrict__ X,
                                               const float* __restrict__ WT,
                                               const float* __restrict__ bias,
                                               const float* __restrict__ extra,
                                               const float* __restrict__ lng,
                                               const float* __restrict__ lnb,
                                               float* __restrict__ Y) {
    constexpr int TM = RPW * 4;
    __shared__ float xs[TM][kD];
    const int t = threadIdx.x;
    const int r0 = blockIdx.x * TM;

    if (MODE == 0) {
#pragma unroll
        for (int it = 0; it < RPW; ++it) {
            const int idx = it * 1024 + t * 4;
            const int r = idx >> 8, c = idx & 255;
            *(f32x4*)&xs[r][c] = *(const f32x4*)(X + (size_t)(r0 + r) * kD + c);
        }
    } else {
#pragma unroll
        for (int it = 0; it < RPW; ++it) {
            const int chunk = it * 32 + (t >> 3);   // 0..TM*8-1
            const int r = chunk >> 3, h = chunk & 7;
            const int row = r0 + r;
            const float* src = X + (((size_t)(row >> 9) * kH + h) * kS + (row & (kS - 1))) * kDK + (t & 7) * 4;
            *(f32x4*)&xs[r][h * kDK + (t & 7) * 4] = *(const f32x4*)src;
        }
    }
    __syncthreads();

    const int wv = t >> 6;
    const int c4 = (t & 63) * 4;
    float acc[RPW][4];
    {
        f32x4 bv = *(const f32x4*)(bias + c4);
#pragma unroll
        for (int r = 0; r < RPW; ++r)
#pragma unroll
            for (int j = 0; j < 4; ++j) acc[r][j] = bv[j];
    }
    for (int k0 = 0; k0 < kD; k0 += 4) {
        f32x4 w0 = *(const f32x4*)(WT + (size_t)(k0 + 0) * kD + c4);
        f32x4 w1 = *(const f32x4*)(WT + (size_t)(k0 + 1) * kD + c4);
        f32x4 w2 = *(const f32x4*)(WT + (size_t)(k0 + 2) * kD + c4);
        f32x4 w3 = *(const f32x4*)(WT + (size_t)(k0 + 3) * kD + c4);
#pragma unroll
        for (int r = 0; r < RPW; ++r) {
            f32x4 xv = *(const f32x4*)&xs[wv * RPW + r][k0];
#pragma unroll
            for (int cc = 0; cc < 4; ++cc) {
                acc[r][cc] = fmaf(xv[0], w0[cc], acc[r][cc]);
                acc[r][cc] = fmaf(xv[1], w1[cc], acc[r][cc]);
                acc[r][cc] = fmaf(xv[2], w2[cc], acc[r][cc]);
                acc[r][cc] = fmaf(xv[3], w3[cc], acc[r][cc]);
            }
        }
    }

#pragma unroll
    for (int r = 0; r < RPW; ++r) {
        const int row = r0 + wv * RPW + r;
        if (MODE == 0) {
            const int h = c4 >> 5, dk = c4 & 31;
            *(f32x4*)(Y + (((size_t)(row >> 9) * kH + h) * kS + (row & (kS - 1))) * kDK + dk) =
                *(f32x4*)acc[r];
        } else {
            f32x4 x;
            if (MODE == 1) {
                f32x4 e = *(const f32x4*)(extra + (size_t)row * kD + c4);
#pragma unroll
                for (int j = 0; j < 4; ++j) x[j] = acc[r][j] + e[j];
            } else {
                const int nk = (row >> 9) & (kNK - 1);
                f32x4 e = *(const f32x4*)(extra + (size_t)nk * kD + c4);
#pragma unroll
                for (int j = 0; j < 4; ++j) x[j] = acc[r][j] + e[j];
            }
            float s1 = x[0] + x[1] + x[2] + x[3];
            float s2 = x[0] * x[0] + x[1] * x[1] + x[2] * x[2] + x[3] * x[3];
#pragma unroll
            for (int off = 32; off; off >>= 1) {
                s1 += __shfl_xor(s1, off);
                s2 += __shfl_xor(s2, off);
            }
            const float mean = s1 * (1.f / kD);
            const float var = s2 * (1.f / kD) - mean * mean;
            const float rstd = rsqrtf(var + 1e-5f);
            f32x4 g = *(const f32x4*)(lng + c4);
            f32x4 bb = *(const f32x4*)(lnb + c4);
            f32x4 y;
#pragma unroll
            for (int j = 0; j < 4; ++j) y[j] = (x[j] - mean) * rstd * g[j] + bb[j];
            if (MODE == 1) {
                *(f32x4*)(Y + (size_t)row * kD + c4) = y;
            } else {
                const int bnk = row >> 9, s = row & (kS - 1);
                const int nk = bnk & (kNK - 1), b = bnk >> 4;
                *(f32x4*)(Y + (((size_t)(b * kS + s) * kNK + nk) * kD) + c4) = y;
            }
        }
    }
}

// Batched MODE-0 GEMM: 3 independent (X, WT, bias, Y) sets, selected by blockIdx.y.
__global__ __launch_bounds__(256) void gemm256_b3(const float* __restrict__ X0,
                                                  const float* __restrict__ WT0,
                                                  const float* __restrict__ b0,
                                                  float* __restrict__ Y0,
                                                  const float* __restrict__ X1,
                                                  const float* __restrict__ WT1,
                                                  const float* __restrict__ b1,
                                                  float* __restrict__ Y1,
                                                  const float* __restrict__ X2,
                                                  const float* __restrict__ WT2,
                                                  const float* __restrict__ b2,
                                                  float* __restrict__ Y2) {
    __shared__ float xs[4][kD];
    const float* X = (blockIdx.y == 0) ? X0 : (blockIdx.y == 1) ? X1 : X2;
    const float* WT = (blockIdx.y == 0) ? WT0 : (blockIdx.y == 1) ? WT1 : WT2;
    const float* bias = (blockIdx.y == 0) ? b0 : (blockIdx.y == 1) ? b1 : b2;
    float* Y = (blockIdx.y == 0) ? Y0 : (blockIdx.y == 1) ? Y1 : Y2;
    const int t = threadIdx.x;
    const int r0 = blockIdx.x * 4;

    {
        const int idx = t * 4;
        const int r = idx >> 8, c = idx & 255;
        *(f32x4*)&xs[r][c] = *(const f32x4*)(X + (size_t)(r0 + r) * kD + c);
    }
    __syncthreads();

    const int wv = t >> 6;
    const int c4 = (t & 63) * 4;
    float acc[4];
    {
        f32x4 bv = *(const f32x4*)(bias + c4);
#pragma unroll
        for (int j = 0; j < 4; ++j) acc[j] = bv[j];
    }
    for (int k0 = 0; k0 < kD; k0 += 4) {
        f32x4 w0 = *(const f32x4*)(WT + (size_t)(k0 + 0) * kD + c4);
        f32x4 w1 = *(const f32x4*)(WT + (size_t)(k0 + 1) * kD + c4);
        f32x4 w2 = *(const f32x4*)(WT + (size_t)(k0 + 2) * kD + c4);
        f32x4 w3 = *(const f32x4*)(WT + (size_t)(k0 + 3) * kD + c4);
        f32x4 xv = *(const f32x4*)&xs[wv][k0];
#pragma unroll
        for (int cc = 0; cc < 4; ++cc) {
            acc[cc] = fmaf(xv[0], w0[cc], acc[cc]);
            acc[cc] = fmaf(xv[1], w1[cc], acc[cc]);
            acc[cc] = fmaf(xv[2], w2[cc], acc[cc]);
            acc[cc] = fmaf(xv[3], w3[cc], acc[cc]);
        }
    }
    const int row = r0 + wv;
    const int h = c4 >> 5, dk = c4 & 31;
    *(f32x4*)(Y + (((size_t)(row >> 9) * kH + h) * kS + (row & (kS - 1))) * kDK + dk) =
        *(f32x4*)acc;
}

// one-row-per-block projection (kept only for tiny Q4: 16 rows)
__global__ __launch_bounds__(256) void proj_kernel(const float* __restrict__ X,
                                                   const float* __restrict__ W,
                                                   const float* __restrict__ bias,
                                                   float* __restrict__ Y, int scatter) {
    const int row = blockIdx.x;
    const int c = threadIdx.x;
    __shared__ float xs[kD];
    xs[c] = X[(size_t)row * kD + c];
    __syncthreads();
    float acc = bias[c];
    const float* wr = W + (size_t)c * kD;
#pragma unroll 4
    for (int k0 = 0; k0 < kD; k0 += 4) {
        f32x4 wv = *(const f32x4*)(wr + k0);
#pragma unroll
        for (int j = 0; j < 4; ++j) acc = fmaf(xs[k0 + j], wv[j], acc);
    }
    if (scatter) {
        const int b = row >> 9, s = row & (kS - 1);
        const int h = c >> 5, dk = c & 31;
        Y[((size_t)(b * kH + h) * kS + s) * kDK + dk] = acc;
    } else {
        Y[(size_t)row * kD + c] = acc;
    }
}

// Block-1 attention v3 (unchanged from round 6)
__global__ __launch_bounds__(256) void attn1_kernel(const float* __restrict__ Q1,
                                                    const float* __restrict__ V1,
                                                    const float* __restrict__ gam,
                                                    float* __restrict__ q_scores,
                                                    float* __restrict__ A1) {
    extern __shared__ char smem[];
    float* Sl = (float*)smem;                               // 32*536 f32 = 68608 B
    u16* Vt = (u16*)(smem + 32 * 536 * 4);                  // 32*520 bf16 = 33280 B
    u16* Pl = (u16*)(smem + 32 * 536 * 4 + 32 * kPS * 2);   // 32*520 bf16 = 33280 B

    const int bh = blockIdx.x;
    const int q0 = blockIdx.y * 32;
    const int h = bh & (kH - 1);
    const int tid = threadIdx.x;
    const int lane = tid & 63;
    const int w = tid >> 6;
    const float* Kb = Q1 + (size_t)bh * kS * kDK;   // K == Q (shared projection)
    const float* Vb = V1 + (size_t)bh * kS * kDK;

#pragma unroll
    for (int it = 0; it < 16; ++it) {
        const int idx = it * 1024 + tid * 4;
        const int k = idx >> 5, d = idx & 31;
        f32x4 v = *(const f32x4*)(Vb + idx);
        Vt[(d + 0) * kPS + k] = f2bf(v[0]);
        Vt[(d + 1) * kPS + k] = f2bf(v[1]);
        Vt[(d + 2) * kPS + k] = f2bf(v[2]);
        Vt[(d + 3) * kPS + k] = f2bf(v[3]);
    }

    {
        const int qt = w & 1, khalf = w >> 1;
        const int qrow = q0 + qt * 16 + (lane & 15);
        const int dof = (lane >> 4) * 8;
        f32x4 qa = *(const f32x4*)(Kb + (size_t)qrow * kDK + dof);
        f32x4 qb = *(const f32x4*)(Kb + (size_t)qrow * kDK + dof + 4);
        s16x8 aq_h, aq_l;
#pragma unroll
        for (int j = 0; j < 4; ++j) {
            float f = qa[j];
            u16 hi = f2bf(f);
            aq_h[j] = (short)hi;
            aq_l[j] = (short)f2bf(f - bf2f(hi));
            f = qb[j];
            hi = f2bf(f);
            aq_h[4 + j] = (short)hi;
            aq_l[4 + j] = (short)f2bf(f - bf2f(hi));
        }
        for (int kt = khalf * 16; kt < khalf * 16 + 16; ++kt) {
            const int krow = kt * 16 + (lane & 15);
            f32x4 ka = *(const f32x4*)(Kb + (size_t)krow * kDK + dof);
            f32x4 kb2 = *(const f32x4*)(Kb + (size_t)krow * kDK + dof + 4);
            s16x8 bk_h, bk_l;
#pragma unroll
            for (int j = 0; j < 4; ++j) {
                float f = ka[j];
                u16 hi = f2bf(f);
                bk_h[j] = (short)hi;
                bk_l[j] = (short)f2bf(f - bf2f(hi));
                f = kb2[j];
                hi = f2bf(f);
                bk_h[4 + j] = (short)hi;
                bk_l[4 + j] = (short)f2bf(f - bf2f(hi));
            }
            f32x4 acc = {0.f, 0.f, 0.f, 0.f};
            acc = __builtin_amdgcn_mfma_f32_16x16x32_bf16(aq_h, bk_h, acc, 0, 0, 0);
            acc = __builtin_amdgcn_mfma_f32_16x16x32_bf16(aq_l, bk_h, acc, 0, 0, 0);
            acc = __builtin_amdgcn_mfma_f32_16x16x32_bf16(aq_h, bk_l, acc, 0, 0, 0);
            const int colk = kt * 16 + (lane & 15);
            const int seg = colk >> 6, ii = colk & 63;
#pragma unroll
            for (int j = 0; j < 4; ++j) {
                const int row = qt * 16 + (lane >> 4) * 4 + j;
                Sl[row * 536 + seg * 67 + ii] = acc[j] * kScale;
            }
        }
    }
    __syncthreads();

    const float gh = -fabsf(gam[h]);
    {
        const int r = tid >> 3, seg = tid & 7;
        const int q = q0 + r, L = q + 1, ks = seg * 64;
        const float* srow = Sl + r * 536 + seg * 67;
        float sv[64];
#pragma unroll
        for (int i = 0; i < 64; ++i) sv[i] = srow[i];
        const int nv = min(max(L - ks, 0), 64);
        float m = -3e38f;
#pragma unroll
        for (int i = 0; i < 64; ++i)
            if (i < nv) m = fmaxf(m, sv[i]);
#pragma unroll
        for (int off = 1; off < 8; off <<= 1) m = fmaxf(m, __shfl_xor(m, off));
        float segsum = 0.f;
#pragma unroll
        for (int i = 0; i < 64; ++i)
            if (i < nv) segsum += __expf(sv[i] - m);
        float tot = segsum;
#pragma unroll
        for (int off = 1; off < 8; off <<= 1) tot += __shfl_xor(tot, off);
        float inc = segsum;
#pragma unroll
        for (int off = 1; off < 8; off <<= 1) {
            const float tmp = __shfl_up(inc, off);
            if ((tid & 7) >= off) inc += tmp;
        }
        float run = inc - segsum;
        const float inv_tot = 1.f / tot;
        float m2 = -3e38f;
#pragma unroll
        for (int i = 0; i < 64; ++i) {
            if (i < nv) {
                const float E = __expf(sv[i] - m);
                run += E;
                const float rem = 1.f - run * inv_tot;
                const float pos = (float)(q - (ks + i));
                const float val = fmaxf(rem * pos, 0.f);
                const float te = fmaxf(__expf(gh * sqrtf(val)), 1e-5f);
                const float s2 = sv[i] * te;
                sv[i] = s2;
                m2 = fmaxf(m2, s2);
            }
        }
#pragma unroll
        for (int off = 1; off < 8; off <<= 1) m2 = fmaxf(m2, __shfl_xor(m2, off));
        float sum2 = 0.f;
#pragma unroll
        for (int i = 0; i < 64; ++i) {
            const float p = (i < nv) ? __expf(sv[i] - m2) : 0.f;
            sv[i] = p;
            sum2 += p;
        }
#pragma unroll
        for (int off = 1; off < 8; off <<= 1) sum2 += __shfl_xor(sum2, off);
        const float inv2 = 1.f / sum2;
        float* qrow = q_scores + ((size_t)bh * kS + q) * kS + ks;
        u16* prow = Pl + r * kPS + ks;
#pragma unroll
        for (int i = 0; i < 64; i += 4) {
            f32x4 o;
            u16x4 pb;
#pragma unroll
            for (int j = 0; j < 4; ++j) {
                const float p = sv[i + j] * inv2;
                o[j] = p;
                pb[j] = f2bf(p);
            }
            *(f32x4*)(qrow + i) = o;
            *(u16x4*)(prow + i) = pb;
        }
    }
    __syncthreads();

    {
        const int qt = w & 1, dt = w >> 1;
        const u16* Arow = Pl + (size_t)(qt * 16 + (lane & 15)) * kPS + (lane >> 4) * 8;
        const u16* Brow = Vt + (size_t)(dt * 16 + (lane & 15)) * kPS + (lane >> 4) * 8;
        f32x4 acc = {0.f, 0.f, 0.f, 0.f};
#pragma unroll
        for (int kc = 0; kc < kS; kc += 32) {
            s16x8 a = *(const s16x8*)(Arow + kc);
            s16x8 b = *(const s16x8*)(Brow + kc);
            acc = __builtin_amdgcn_mfma_f32_16x16x32_bf16(a, b, acc, 0, 0, 0);
        }
        const int d = dt * 16 + (lane & 15);
#pragma unroll
        for (int j = 0; j < 4; ++j) {
            const int row = qt * 16 + (lane >> 4) * 4 + j;
            A1[((size_t)bh * kS + (q0 + row)) * kDK + d] = acc[j];
        }
    }
}

// Block-4 prep (unchanged)
__global__ __launch_bounds__(64) void attn4_prep(const float* __restrict__ Q4,
                                                 const float* __restrict__ K4,
                                                 float* __restrict__ rawP,
                                                 float* __restrict__ CpreP) {
    const int panel = blockIdx.x;
    const int h = panel & (kH - 1);
    const int bnk = panel >> 3;
    const int nk = bnk & (kNK - 1);
    const int b = bnk >> 4;
    const int lane = threadIdx.x;
    const float* Kp = K4 + (size_t)(b * kH + h) * kS * kDK;
    float qv[kDK];
    const float* Qr = Q4 + (size_t)nk * kD + h * kDK;
#pragma unroll
    for (int d = 0; d < kDK; ++d) qv[d] = Qr[d];

    const int k0 = lane * 8;
    float raw[8];
    float m = -3e38f;
#pragma unroll
    for (int j = 0; j < 8; ++j) {
        const float* kr = Kp + (size_t)(k0 + j) * kDK;
        float s = 0.f;
#pragma unroll
        for (int d = 0; d < kDK; ++d) s = fmaf(qv[d], kr[d], s);
        raw[j] = s * kScale;
        m = fmaxf(m, raw[j]);
    }
    m = wave_max64(m);
    float E[8];
    float s = 0.f;
#pragma unroll
    for (int j = 0; j < 8; ++j) { E[j] = __expf(raw[j] - m); s += E[j]; }
    float inc = s;
#pragma unroll
    for (int off = 1; off < 64; off <<= 1) {
        float t = __shfl_up(inc, off);
        if (lane >= off) inc += t;
    }
    float run = inc - s;
    float cp[8];
#pragma unroll
    for (int j = 0; j < 8; ++j) { run += E[j]; cp[j] = run; }

    float* rrow = rawP + (size_t)panel * kS + k0;
    float* crow = CpreP + (size_t)panel * kS + k0;
    *(f32x4*)(rrow) = *(f32x4*)(raw);
    *(f32x4*)(rrow + 4) = *(f32x4*)(raw + 4);
    *(f32x4*)(crow) = *(f32x4*)(cp);
    *(f32x4*)(crow + 4) = *(f32x4*)(cp + 4);
}

// Block-4 main v4: fused softmax; PV B-fragments from global Vtg; LDS 37376 B
__global__ __launch_bounds__(256) void attn4_main(const float* __restrict__ rawP,
                                                  const float* __restrict__ CpreP,
                                                  const u16* __restrict__ Vtg,
                                                  const float* __restrict__ gam,
                                                  float* __restrict__ k_scores,
                                                  float* __restrict__ A4) {
    extern __shared__ char smem[];
    u16* Pl = (u16*)smem;                           // [32][kPS] bf16
    float* raws_l = (float*)(smem + 32 * kPS * 2);  // [512]
    float* cps_l = raws_l + kS;                     // [512]

    const int panel = blockIdx.x;        // (b*NK + nk)*H + h
    const int q0 = blockIdx.y * 32;
    const int h = panel & (kH - 1);
    const int bnk = panel >> 3;
    const int nk = bnk & (kNK - 1);
    const int b = bnk >> 4;
    const int tid = threadIdx.x;
    const int lane = tid & 63;
    const int w = tid >> 6;

    for (int i = tid; i < kS; i += 256) {
        raws_l[i] = rawP[(size_t)panel * kS + i];
        cps_l[i] = CpreP[(size_t)panel * kS + i];
    }
    __syncthreads();

    const float gh = -fabsf(gam[h]);
    const int rbase = w * 8;
    const int k0 = lane * 8;
    float rw[8], cp[8];
    *(f32x4*)(rw) = *(const f32x4*)(raws_l + k0);
    *(f32x4*)(rw + 4) = *(const f32x4*)(raws_l + k0 + 4);
    *(f32x4*)(cp) = *(const f32x4*)(cps_l + k0);
    *(f32x4*)(cp + 4) = *(const f32x4*)(cps_l + k0 + 4);

    for (int r = 0; r < 8; ++r) {
        const int row = rbase + r;
        const int Lr = q0 + row;         // strict mask: k < Lr
        float* krow = k_scores + ((size_t)((b * kH + h) * kS + Lr) * kNK + nk) * kS;
        u16* prow = Pl + (size_t)row * kPS + k0;
        if (Lr == 0) {
            f32x4 z = {0.f, 0.f, 0.f, 0.f};
            *(f32x4*)(krow + k0) = z;
            *(f32x4*)(krow + k0 + 4) = z;
            u16x8 zb = {0, 0, 0, 0, 0, 0, 0, 0};
            *(u16x8*)(prow) = zb;
            continue;
        }
        const float invCL = 1.f / cps_l[Lr - 1];
        const float fL = (float)(Lr - k0);
        float s2v[8];
        float mloc = -3e38f;
#pragma unroll
        for (int j = 0; j < 8; ++j) {
            const float rem = 1.f - cp[j] * invCL;
            const float val = fmaxf(rem * (fL - (float)j), 0.f);
            const float te = fmaxf(__expf(gh * sqrtf(val)), 1e-5f);
            const float s2 = rw[j] * te;
            s2v[j] = s2;
            if (k0 + j < Lr) mloc = fmaxf(mloc, s2);
        }
        const float m2 = wave_max64(mloc);
        float p[8];
        float psum = 0.f;
#pragma unroll
        for (int j = 0; j < 8; ++j) {
            p[j] = (k0 + j < Lr) ? __expf(s2v[j] - m2) : 0.f;
            psum += p[j];
        }
        const float sum2 = wave_sum64(psum);
        const float scl = fminf(sum2, 5.f) / sum2;   // maxout folded
        u16x8 pb;
#pragma unroll
        for (int j = 0; j < 8; ++j) {
            p[j] *= scl;
            pb[j] = f2bf(p[j]);
        }
        *(f32x4*)(krow + k0) = *(f32x4*)(p);
        *(f32x4*)(krow + k0 + 4) = *(f32x4*)(p + 4);
        *(u16x8*)(prow) = pb;
    }
    __syncthreads();

    // MFMA PV: A from LDS Pl, B from global Vtg [bh][d][k] bf16
    const int rowblk = (w & 1) * 16;
    const int dblk = (w >> 1) * 16;
    const u16* Arow = Pl + (size_t)(rowblk + (lane & 15)) * kPS + (lane >> 4) * 8;
    const u16* Brow = Vtg + ((size_t)(b * kH + h) * kDK + dblk + (lane & 15)) * kS + (lane >> 4) * 8;
    f32x4 acc = {0.f, 0.f, 0.f, 0.f};
#pragma unroll
    for (int kc = 0; kc < kS; kc += 32) {
        s16x8 a = *(const s16x8*)(Arow + kc);
        s16x8 bfr = *(const s16x8*)(Brow + kc);
        acc = __builtin_amdgcn_mfma_f32_16x16x32_bf16(a, bfr, acc, 0, 0, 0);
    }
    const int d = dblk + (lane & 15);
#pragma unroll
    for (int j = 0; j < 4; ++j) {
        const int row = rowblk + (lane >> 4) * 4 + j;
        A4[((size_t)panel * kS + (q0 + row)) * kDK + d] = acc[j];
    }
}

extern "C" void kernel_launch(void* const* d_in, const int* in_sizes, int n_in,
                              void* d_out, int out_size, void* d_ws, size_t ws_size,
                              hipStream_t stream) {
    (void)in_sizes; (void)n_in; (void)out_size; (void)ws_size;

    const float* q_emb = (const float*)d_in[0];
    const float* s_emb = (const float*)d_in[1];
    const float* Wq1 = (const float*)d_in[5];  const float* bq1 = (const float*)d_in[6];
    const float* Wv1 = (const float*)d_in[7];  const float* bv1 = (const float*)d_in[8];
    const float* Wo1 = (const float*)d_in[9];  const float* bo1 = (const float*)d_in[10];
    const float* gam1 = (const float*)d_in[11];
    const float* ln1g = (const float*)d_in[12]; const float* ln1b = (const float*)d_in[13];
    const float* Wq4 = (const float*)d_in[14]; const float* bq4 = (const float*)d_in[15];
    const float* Wk4 = (const float*)d_in[16]; const float* bk4 = (const float*)d_in[17];
    const float* Wv4 = (const float*)d_in[18]; const float* bv4 = (const float*)d_in[19];
    const float* Wo4 = (const float*)d_in[20]; const float* bo4 = (const float*)d_in[21];
    const float* gam4 = (const float*)d_in[22];
    const float* ln4g = (const float*)d_in[23]; const float* ln4b = (const float*)d_in[24];
    const float* know = (const float*)d_in[25];

    float* ws = (float*)d_ws;
    const size_t NBHSD = (size_t)kB * kH * kS * kDK;       // 262144
    float* Q1 = ws;
    float* V1 = Q1 + NBHSD;                                 // freed after attn1 -> rawP/CpreP
    float* A1 = V1 + NBHSD;
    float* P  = A1 + NBHSD;
    float* K4 = P  + (size_t)kB * kS * kD;
    float* V4 = K4 + NBHSD;
    float* Q4 = V4 + NBHSD;                                 // NK*D = 4096
    float* A4 = Q4 + (size_t)kNK * kD;                      // 4194304
    float* WT = A4 + (size_t)kB * kNK * kH * kS * kDK;      // 6 * 65536 floats
    u16* Vtg = (u16*)(WT + 6 * (size_t)kD * kD);            // 16*32*512 bf16

    float* rawP = V1;
    float* CpreP = V1 + (size_t)kB * kNK * kH * kS;

    float* WTq1 = WT + 0 * (size_t)kD * kD;
    float* WTv1 = WT + 1 * (size_t)kD * kD;
    float* WTo1 = WT + 2 * (size_t)kD * kD;
    float* WTk4 = WT + 3 * (size_t)kD * kD;
    float* WTv4 = WT + 4 * (size_t)kD * kD;
    float* WTo4 = WT + 5 * (size_t)kD * kD;

    float* zout = (float*)d_out;
    float* q_scores = zout + (size_t)kB * kS * kNK * kD;
    float* k_scores = q_scores + (size_t)kB * kH * kS * kS;

    {
        dim3 g(kD, 6);
        wt_kernel<<<g, 256, 0, stream>>>(Wq1, Wv1, Wo1, Wk4, Wv4, Wo4, WT);
    }
    {
        dim3 g(kB * kS / 4, 3);
        gemm256_b3<<<g, 256, 0, stream>>>(q_emb, WTq1, bq1, Q1,
                                          s_emb, WTv1, bv1, V1,
                                          q_emb, WTk4, bk4, K4);
    }
    proj_kernel<<<kNK, 256, 0, stream>>>(know, Wq4, bq4, Q4, 0);

    // Block 1
    {
        dim3 g1(kB * kH, kS / 32);
        const int lds1 = 32 * 536 * 4 + 2 * 32 * kPS * 2;   // 135168
        attn1_kernel<<<g1, 256, lds1, stream>>>(Q1, V1, gam1, q_scores, A1);
    }
    gemm256<1, 1><<<kB * kS / 4, 256, 0, stream>>>(A1, WTo1, bo1, q_emb, ln1g, ln1b, P);

    // Block 4 (V1 dead from here; reused as rawP/CpreP)
    gemm256<1, 0><<<kB * kS / 4, 256, 0, stream>>>(P, WTv4, bv4, nullptr, nullptr, nullptr, V4);
    {
        dim3 gv(kB * kH, 4);
        vt4_kernel<<<gv, 256, 0, stream>>>(V4, Vtg);
    }
    attn4_prep<<<kB * kNK * kH, 64, 0, stream>>>(Q4, K4, rawP, CpreP);
    {
        dim3 g5(kB * kNK * kH, kS / 32);
        const int lds_bytes = 32 * kPS * 2 + 2 * kS * 4;    // 37376
        attn4_main<<<g5, 256, lds_bytes, stream>>>(rawP, CpreP, Vtg, gam4, k_scores, A4);
    }
    gemm256<4, 2><<<kB * kNK * kS / 16, 256, 0, stream>>>(A4, WTo4, bo4, know, ln4g, ln4b, zout);
}